// Round 15
// baseline (276.116 us; speedup 1.0000x reference)
//
#include <hip/hip_runtime.h>
#include <hip/hip_bf16.h>

typedef __attribute__((ext_vector_type(4))) float f32x4;
typedef __attribute__((ext_vector_type(16))) float f32x16;
typedef __attribute__((ext_vector_type(8))) short bf16x8;
typedef __attribute__((ext_vector_type(4))) unsigned int uint4v;
typedef __attribute__((ext_vector_type(2))) unsigned int uint2v;

#define MFMA16(a, b, c) __builtin_amdgcn_mfma_f32_16x16x32_bf16(a, b, c, 0, 0, 0)
#define MFMA32(a, b, c) __builtin_amdgcn_mfma_f32_32x32x16_bf16(a, b, c, 0, 0, 0)

__device__ __forceinline__ unsigned short f2bf(float f) {
  union { float f; unsigned u; } v; v.f = f;
  unsigned r = v.u + 0x7fffu + ((v.u >> 16) & 1u);
  return (unsigned short)(r >> 16);
}
__device__ __forceinline__ unsigned pack2(float a, float b) {
  union { __hip_bfloat162 h2; unsigned u; } cv;
  cv.h2 = __hip_bfloat162(__float2bfloat16(a), __float2bfloat16(b));
  return cv.u;
}

// cross-half exchange (validated R10-R14)
__device__ __forceinline__ void swap32(unsigned a, unsigned b, int hi,
                                       unsigned& ox, unsigned& oy) {
#if __has_builtin(__builtin_amdgcn_permlane32_swap)
  uint2v r = __builtin_amdgcn_permlane32_swap(a, b, false, false);
  ox = r[0]; oy = r[1];
#else
  unsigned sb = __shfl_xor(b, 32);
  unsigned sa = __shfl_xor(a, 32);
  ox = hi ? sb : a;
  oy = hi ? b : sa;
#endif
}

// y = x @ W^T + b, M=65536 rows, N=K=128.
// OUT_MODE: 0 = bf16 [M][128]; 1 = bf16 transposed [B][128][2048]; 2 = f32 [M][128]
template<bool IN_F32, int OUT_MODE>
__global__ __launch_bounds__(256)
void proj_kernel(const void* __restrict__ xin, const float* __restrict__ W,
                 const float* __restrict__ bias, void* __restrict__ yout,
                 float scale)
{
  __shared__ __align__(16) unsigned short Ws[128][136];
  __shared__ __align__(16) unsigned short Xs[64][136];
  const int t = threadIdx.x;
  const int wid = t >> 6;
  const int lane = t & 63;
  const int ln = lane & 15, g = lane >> 4;
  const long row0 = (long)blockIdx.x * 64;

  float bz[8];
#pragma unroll
  for (int tt = 0; tt < 8; ++tt) bz[tt] = bias[tt * 16 + ln];

#pragma unroll
  for (int i = 0; i < 16; ++i) {
    int idx = (i * 256 + t) * 4;
    int r = idx >> 7, c = idx & 127;
    const float4 w4 = *reinterpret_cast<const float4*>(W + idx);
    ushort4 wb;
    wb.x = f2bf(w4.x); wb.y = f2bf(w4.y); wb.z = f2bf(w4.z); wb.w = f2bf(w4.w);
    *reinterpret_cast<ushort4*>(&Ws[r][c]) = wb;
  }
  if (IN_F32) {
    const float* x = (const float*)xin;
#pragma unroll
    for (int i = 0; i < 8; ++i) {
      int idx = (i * 256 + t) * 4;
      int r = idx >> 7, c = idx & 127;
      const float4 x4 = *reinterpret_cast<const float4*>(x + row0 * 128 + idx);
      ushort4 xb;
      xb.x = f2bf(x4.x); xb.y = f2bf(x4.y); xb.z = f2bf(x4.z); xb.w = f2bf(x4.w);
      *reinterpret_cast<ushort4*>(&Xs[r][c]) = xb;
    }
  } else {
    const unsigned short* x = (const unsigned short*)xin;
#pragma unroll
    for (int i = 0; i < 4; ++i) {
      int idx = (i * 256 + t) * 8;
      int r = idx >> 7, c = idx & 127;
      *reinterpret_cast<uint4v*>(&Xs[r][c]) =
          *reinterpret_cast<const uint4v*>(x + row0 * 128 + idx);
    }
  }
  __syncthreads();

  f32x4 acc[8];
#pragma unroll
  for (int tt = 0; tt < 8; ++tt) acc[tt] = (f32x4){0.f, 0.f, 0.f, 0.f};

#pragma unroll
  for (int c = 0; c < 4; ++c) {
    bf16x8 af = *reinterpret_cast<const bf16x8*>(&Xs[wid * 16 + ln][c * 32 + g * 8]);
#pragma unroll
    for (int tt = 0; tt < 8; ++tt) {
      bf16x8 bfr = *reinterpret_cast<const bf16x8*>(&Ws[tt * 16 + ln][c * 32 + g * 8]);
      acc[tt] = MFMA16(af, bfr, acc[tt]);
    }
  }

#pragma unroll
  for (int tt = 0; tt < 8; ++tt) {
#pragma unroll
    for (int r = 0; r < 4; ++r) {
      long row = row0 + wid * 16 + g * 4 + r;
      int col = tt * 16 + ln;
      float val = (acc[tt][r] + bz[tt]) * scale;
      if (OUT_MODE == 2) {
        ((float*)yout)[row * 128 + col] = val;
      } else if (OUT_MODE == 0) {
        ((unsigned short*)yout)[row * 128 + col] = f2bf(val);
      } else {
        long bb = row >> 11, rr = row & 2047;
        ((unsigned short*)yout)[(bb * 128 + col) * 2048 + rr] = f2bf(val);
      }
    }
  }
}

// Fused K+V projection (R13-proven): stages X once, two weight phases.
__global__ __launch_bounds__(256)
void proj_kv_kernel(const float* __restrict__ x,
                    const float* __restrict__ Wk, const float* __restrict__ bk,
                    const float* __restrict__ Wv, const float* __restrict__ bv,
                    unsigned short* __restrict__ Kout,
                    unsigned short* __restrict__ Vout)
{
  __shared__ __align__(16) unsigned short Ws[128][136];
  __shared__ __align__(16) unsigned short Xs[64][136];
  const int t = threadIdx.x;
  const int wid = t >> 6;
  const int lane = t & 63;
  const int ln = lane & 15, g = lane >> 4;
  const long row0 = (long)blockIdx.x * 64;

  float bzk[8], bzv[8];
#pragma unroll
  for (int tt = 0; tt < 8; ++tt) { bzk[tt] = bk[tt * 16 + ln]; bzv[tt] = bv[tt * 16 + ln]; }

#pragma unroll
  for (int i = 0; i < 8; ++i) {
    int idx = (i * 256 + t) * 4;
    int r = idx >> 7, c = idx & 127;
    const float4 x4 = *reinterpret_cast<const float4*>(x + row0 * 128 + idx);
    ushort4 xb;
    xb.x = f2bf(x4.x); xb.y = f2bf(x4.y); xb.z = f2bf(x4.z); xb.w = f2bf(x4.w);
    *reinterpret_cast<ushort4*>(&Xs[r][c]) = xb;
  }
#pragma unroll
  for (int i = 0; i < 16; ++i) {
    int idx = (i * 256 + t) * 4;
    int r = idx >> 7, c = idx & 127;
    const float4 w4 = *reinterpret_cast<const float4*>(Wk + idx);
    ushort4 wb;
    wb.x = f2bf(w4.x); wb.y = f2bf(w4.y); wb.z = f2bf(w4.z); wb.w = f2bf(w4.w);
    *reinterpret_cast<ushort4*>(&Ws[r][c]) = wb;
  }
  __syncthreads();

  f32x4 acc[8];
#pragma unroll
  for (int tt = 0; tt < 8; ++tt) acc[tt] = (f32x4){0.f, 0.f, 0.f, 0.f};
#pragma unroll
  for (int c = 0; c < 4; ++c) {
    bf16x8 af = *reinterpret_cast<const bf16x8*>(&Xs[wid * 16 + ln][c * 32 + g * 8]);
#pragma unroll
    for (int tt = 0; tt < 8; ++tt) {
      bf16x8 bfr = *reinterpret_cast<const bf16x8*>(&Ws[tt * 16 + ln][c * 32 + g * 8]);
      acc[tt] = MFMA16(af, bfr, acc[tt]);
    }
  }
#pragma unroll
  for (int tt = 0; tt < 8; ++tt)
#pragma unroll
    for (int r = 0; r < 4; ++r) {
      long row = row0 + wid * 16 + g * 4 + r;
      Kout[row * 128 + tt * 16 + ln] = f2bf(acc[tt][r] + bzk[tt]);
    }

  __syncthreads();
#pragma unroll
  for (int i = 0; i < 16; ++i) {
    int idx = (i * 256 + t) * 4;
    int r = idx >> 7, c = idx & 127;
    const float4 w4 = *reinterpret_cast<const float4*>(Wv + idx);
    ushort4 wb;
    wb.x = f2bf(w4.x); wb.y = f2bf(w4.y); wb.z = f2bf(w4.z); wb.w = f2bf(w4.w);
    *reinterpret_cast<ushort4*>(&Ws[r][c]) = wb;
  }
  __syncthreads();

#pragma unroll
  for (int tt = 0; tt < 8; ++tt) acc[tt] = (f32x4){0.f, 0.f, 0.f, 0.f};
#pragma unroll
  for (int c = 0; c < 4; ++c) {
    bf16x8 af = *reinterpret_cast<const bf16x8*>(&Xs[wid * 16 + ln][c * 32 + g * 8]);
#pragma unroll
    for (int tt = 0; tt < 8; ++tt) {
      bf16x8 bfr = *reinterpret_cast<const bf16x8*>(&Ws[tt * 16 + ln][c * 32 + g * 8]);
      acc[tt] = MFMA16(af, bfr, acc[tt]);
    }
  }
#pragma unroll
  for (int tt = 0; tt < 8; ++tt)
#pragma unroll
    for (int r = 0; r < 4; ++r) {
      long row = row0 + wid * 16 + g * 4 + r;
      long bb = row >> 11, rr = row & 2047;
      Vout[(bb * 128 + tt * 16 + ln) * 2048 + rr] = f2bf(acc[tt][r] + bzv[tt]);
    }
}

// Flash attention, LDS-FREE: K/V tiles are L2-resident (XCD swizzle, proven
// 24.7MB FETCH in R14) and the 16KB/iter working set is L1-cacheable; staging
// them in LDS was pure overhead (saturated LDS pipe). Fragments read directly
// from global; no barriers; each wave independent. R12 softmax/P-exchange body.
__global__ __launch_bounds__(256)
void attn_kernel(const unsigned short* __restrict__ Qg,
                 const unsigned short* __restrict__ Kg,
                 const unsigned short* __restrict__ Vtg,
                 unsigned short* __restrict__ Fg)
{
  const int t = threadIdx.x;          // 0..255
  const int lane = t & 63;
  const int q = lane & 31;
  const int hi = lane >> 5;
  const int wid = t >> 6;

  // XCD swizzle: all 16 q-blocks of a batch on one XCD (bid%8 round-robin)
  const int gbid = blockIdx.x;
  const int k_ = gbid >> 3, r_ = gbid & 7;
  const int b = r_ + 8 * (k_ >> 4);
  const int j = k_ & 15;
  const int q0 = j * 128 + wid * 32;

  const unsigned short* Qb = Qg + (long)b * 2048 * 128;
  const unsigned short* Kb = Kg + (long)b * 2048 * 128;
  const unsigned short* Vb = Vtg + (long)b * 128 * 2048;

  // per-lane fragment base pointers (advance kv each iteration)
  const unsigned short* kp = Kb + (long)q * 128 + hi * 8;          // + c*16, + kv*128
  const unsigned short* vp0 = Vb + (long)q * 2048 + hi * 8;        // row d=dc*32+q: + dc*32*2048, + kv
  bf16x8 qf[8];
#pragma unroll
  for (int c = 0; c < 8; ++c)
    qf[c] = *reinterpret_cast<const bf16x8*>(
        Qb + (long)(q0 + q) * 128 + c * 16 + hi * 8);

  f32x16 o[4];
#pragma unroll
  for (int dc = 0; dc < 4; ++dc)
#pragma unroll
    for (int r = 0; r < 16; ++r) o[dc][r] = 0.f;
  float mrun = -1e30f;
  float lrun = 0.f;

  for (int kt = 0; kt < 64; ++kt) {
    const long kv0 = (long)kt * 32;

    // QK^T: A-frag = K[kv0+q][c*16+hi*8 ..], direct from global (L1/L2-hit)
    f32x16 st;
#pragma unroll
    for (int r = 0; r < 16; ++r) st[r] = 0.f;
    __builtin_amdgcn_s_setprio(1);
#pragma unroll
    for (int c = 0; c < 8; ++c) {
      bf16x8 kf = *reinterpret_cast<const bf16x8*>(kp + kv0 * 128 + c * 16);
      st = MFMA32(kf, qf[c], st);
    }
    __builtin_amdgcn_s_setprio(0);

    float tm = st[0];
#pragma unroll
    for (int r = 1; r < 16; ++r) tm = fmaxf(tm, st[r]);
    tm = fmaxf(tm, __shfl_xor(tm, 32));

    float mcur = mrun;
    if (!__all(tm <= mcur + 8.0f)) {
      float mnew = fmaxf(mcur, tm);
      float al = __builtin_amdgcn_exp2f(mcur - mnew);
      mrun = mnew;
      mcur = mnew;
      lrun *= al;
#pragma unroll
      for (int r = 0; r < 16; ++r) {
        float ar = __shfl(al, (r & 3) + 8 * (r >> 2) + 4 * hi);
#pragma unroll
        for (int dc = 0; dc < 4; ++dc) o[dc][r] *= ar;
      }
    }

    unsigned pk[8];
    float s[8];
#pragma unroll
    for (int j2 = 0; j2 < 8; ++j2) {
      float pa_ = __builtin_amdgcn_exp2f(st[2 * j2] - mcur);
      float pb_ = __builtin_amdgcn_exp2f(st[2 * j2 + 1] - mcur);
      s[j2] = pa_ + pb_;
      pk[j2] = pack2(pa_, pb_);
    }
#pragma unroll
    for (int j2 = 0; j2 < 4; ++j2) s[j2] += s[j2 + 4];
    lrun += (s[0] + s[1]) + (s[2] + s[3]);

    union { unsigned u[4]; bf16x8 v; } pa0, pa1;
    swap32(pk[0], pk[2], hi, pa0.u[0], pa0.u[2]);
    swap32(pk[1], pk[3], hi, pa0.u[1], pa0.u[3]);
    swap32(pk[4], pk[6], hi, pa1.u[0], pa1.u[2]);
    swap32(pk[5], pk[7], hi, pa1.u[1], pa1.u[3]);

    // PV: B-frag = V^T[d=dc*32+q][kv0 + {0,16} + hi*8 ..], direct from global
    __builtin_amdgcn_s_setprio(1);
#pragma unroll
    for (int dc = 0; dc < 4; ++dc) {
      const unsigned short* vr = vp0 + (long)dc * 32 * 2048 + kv0;
      bf16x8 vf0 = *reinterpret_cast<const bf16x8*>(vr);
      bf16x8 vf1 = *reinterpret_cast<const bf16x8*>(vr + 16);
      o[dc] = MFMA32(pa0.v, vf0, o[dc]);
      o[dc] = MFMA32(pa1.v, vf1, o[dc]);
    }
    __builtin_amdgcn_s_setprio(0);
  }

  float ltot = lrun + __shfl_xor(lrun, 32);
  float inv = 1.f / ltot;
#pragma unroll
  for (int r = 0; r < 16; ++r) {
    const int qr = (r & 3) + 8 * (r >> 2) + 4 * hi;
    float invr = __shfl(inv, qr);
    long row = (long)b * 2048 + q0 + qr;
#pragma unroll
    for (int dc = 0; dc < 4; ++dc)
      Fg[row * 128 + dc * 32 + q] = f2bf(o[dc][r] * invr);
  }
}

extern "C" void kernel_launch(void* const* d_in, const int* in_sizes, int n_in,
                              void* d_out, int out_size, void* d_ws, size_t ws_size,
                              hipStream_t stream)
{
  (void)in_sizes; (void)n_in; (void)out_size; (void)ws_size;
  const float* smiles = (const float*)d_in[0];
  const float* image  = (const float*)d_in[1];
  const float* Wv = (const float*)d_in[2]; const float* bv = (const float*)d_in[3];
  const float* Wk = (const float*)d_in[4]; const float* bk = (const float*)d_in[5];
  const float* Wq = (const float*)d_in[6]; const float* bq = (const float*)d_in[7];
  const float* Wd = (const float*)d_in[8]; const float* bd = (const float*)d_in[9];

  unsigned short* Qw = (unsigned short*)d_ws;          // [32][2048][128] bf16
  unsigned short* Kw = Qw + 8388608;                   // [32][2048][128] bf16
  unsigned short* Vw = Kw + 8388608;                   // [32][128][2048] bf16 (V^T)
  unsigned short* Fw = Vw + 8388608;                   // [32][2048][128] bf16 fusion

  const float qscale = 1.4426950408889634f * 0.08838834764831845f;

  dim3 blk(256);
  proj_kernel<true, 0><<<dim3(1024), blk, 0, stream>>>(image, Wq, bq, Qw, qscale);
  proj_kv_kernel<<<dim3(1024), blk, 0, stream>>>(smiles, Wk, bk, Wv, bv, Kw, Vw);
  attn_kernel<<<dim3(512), blk, 0, stream>>>(Qw, Kw, Vw, Fw);
  proj_kernel<false, 2><<<dim3(1024), blk, 0, stream>>>(Fw, Wd, bd, (float*)d_out, 1.f);
}

// Round 16
// 170.177 us; speedup vs baseline: 1.6225x; 1.6225x over previous
//
#include <hip/hip_runtime.h>
#include <hip/hip_bf16.h>

typedef __attribute__((ext_vector_type(4))) float f32x4;
typedef __attribute__((ext_vector_type(16))) float f32x16;
typedef __attribute__((ext_vector_type(8))) short bf16x8;
typedef __attribute__((ext_vector_type(4))) unsigned int uint4v;
typedef __attribute__((ext_vector_type(2))) unsigned int uint2v;

#define MFMA16(a, b, c) __builtin_amdgcn_mfma_f32_16x16x32_bf16(a, b, c, 0, 0, 0)
#define MFMA32(a, b, c) __builtin_amdgcn_mfma_f32_32x32x16_bf16(a, b, c, 0, 0, 0)

__device__ __forceinline__ unsigned short f2bf(float f) {
  union { float f; unsigned u; } v; v.f = f;
  unsigned r = v.u + 0x7fffu + ((v.u >> 16) & 1u);
  return (unsigned short)(r >> 16);
}
__device__ __forceinline__ unsigned pack2(float a, float b) {
  union { __hip_bfloat162 h2; unsigned u; } cv;
  cv.h2 = __hip_bfloat162(__float2bfloat16(a), __float2bfloat16(b));
  return cv.u;
}

// cross-half exchange (validated R10-R14)
__device__ __forceinline__ void swap32(unsigned a, unsigned b, int hi,
                                       unsigned& ox, unsigned& oy) {
#if __has_builtin(__builtin_amdgcn_permlane32_swap)
  uint2v r = __builtin_amdgcn_permlane32_swap(a, b, false, false);
  ox = r[0]; oy = r[1];
#else
  unsigned sb = __shfl_xor(b, 32);
  unsigned sa = __shfl_xor(a, 32);
  ox = hi ? sb : a;
  oy = hi ? b : sa;
#endif
}

// y = x @ W^T + b, M=65536 rows, N=K=128.
// OUT_MODE: 0 = bf16 [M][128]; 1 = bf16 transposed [B][128][2048]; 2 = f32 [M][128]
template<bool IN_F32, int OUT_MODE>
__global__ __launch_bounds__(256)
void proj_kernel(const void* __restrict__ xin, const float* __restrict__ W,
                 const float* __restrict__ bias, void* __restrict__ yout,
                 float scale)
{
  __shared__ __align__(16) unsigned short Ws[128][136];
  __shared__ __align__(16) unsigned short Xs[64][136];
  const int t = threadIdx.x;
  const int wid = t >> 6;
  const int lane = t & 63;
  const int ln = lane & 15, g = lane >> 4;
  const long row0 = (long)blockIdx.x * 64;

  float bz[8];
#pragma unroll
  for (int tt = 0; tt < 8; ++tt) bz[tt] = bias[tt * 16 + ln];

#pragma unroll
  for (int i = 0; i < 16; ++i) {
    int idx = (i * 256 + t) * 4;
    int r = idx >> 7, c = idx & 127;
    const float4 w4 = *reinterpret_cast<const float4*>(W + idx);
    ushort4 wb;
    wb.x = f2bf(w4.x); wb.y = f2bf(w4.y); wb.z = f2bf(w4.z); wb.w = f2bf(w4.w);
    *reinterpret_cast<ushort4*>(&Ws[r][c]) = wb;
  }
  if (IN_F32) {
    const float* x = (const float*)xin;
#pragma unroll
    for (int i = 0; i < 8; ++i) {
      int idx = (i * 256 + t) * 4;
      int r = idx >> 7, c = idx & 127;
      const float4 x4 = *reinterpret_cast<const float4*>(x + row0 * 128 + idx);
      ushort4 xb;
      xb.x = f2bf(x4.x); xb.y = f2bf(x4.y); xb.z = f2bf(x4.z); xb.w = f2bf(x4.w);
      *reinterpret_cast<ushort4*>(&Xs[r][c]) = xb;
    }
  } else {
    const unsigned short* x = (const unsigned short*)xin;
#pragma unroll
    for (int i = 0; i < 4; ++i) {
      int idx = (i * 256 + t) * 8;
      int r = idx >> 7, c = idx & 127;
      *reinterpret_cast<uint4v*>(&Xs[r][c]) =
          *reinterpret_cast<const uint4v*>(x + row0 * 128 + idx);
    }
  }
  __syncthreads();

  f32x4 acc[8];
#pragma unroll
  for (int tt = 0; tt < 8; ++tt) acc[tt] = (f32x4){0.f, 0.f, 0.f, 0.f};

#pragma unroll
  for (int c = 0; c < 4; ++c) {
    bf16x8 af = *reinterpret_cast<const bf16x8*>(&Xs[wid * 16 + ln][c * 32 + g * 8]);
#pragma unroll
    for (int tt = 0; tt < 8; ++tt) {
      bf16x8 bfr = *reinterpret_cast<const bf16x8*>(&Ws[tt * 16 + ln][c * 32 + g * 8]);
      acc[tt] = MFMA16(af, bfr, acc[tt]);
    }
  }

#pragma unroll
  for (int tt = 0; tt < 8; ++tt) {
#pragma unroll
    for (int r = 0; r < 4; ++r) {
      long row = row0 + wid * 16 + g * 4 + r;
      int col = tt * 16 + ln;
      float val = (acc[tt][r] + bz[tt]) * scale;
      if (OUT_MODE == 2) {
        ((float*)yout)[row * 128 + col] = val;
      } else if (OUT_MODE == 0) {
        ((unsigned short*)yout)[row * 128 + col] = f2bf(val);
      } else {
        long bb = row >> 11, rr = row & 2047;
        ((unsigned short*)yout)[(bb * 128 + col) * 2048 + rr] = f2bf(val);
      }
    }
  }
}

// Fused K+V projection (R13-proven): stages X once, two weight phases.
__global__ __launch_bounds__(256)
void proj_kv_kernel(const float* __restrict__ x,
                    const float* __restrict__ Wk, const float* __restrict__ bk,
                    const float* __restrict__ Wv, const float* __restrict__ bv,
                    unsigned short* __restrict__ Kout,
                    unsigned short* __restrict__ Vout)
{
  __shared__ __align__(16) unsigned short Ws[128][136];
  __shared__ __align__(16) unsigned short Xs[64][136];
  const int t = threadIdx.x;
  const int wid = t >> 6;
  const int lane = t & 63;
  const int ln = lane & 15, g = lane >> 4;
  const long row0 = (long)blockIdx.x * 64;

  float bzk[8], bzv[8];
#pragma unroll
  for (int tt = 0; tt < 8; ++tt) { bzk[tt] = bk[tt * 16 + ln]; bzv[tt] = bv[tt * 16 + ln]; }

#pragma unroll
  for (int i = 0; i < 8; ++i) {
    int idx = (i * 256 + t) * 4;
    int r = idx >> 7, c = idx & 127;
    const float4 x4 = *reinterpret_cast<const float4*>(x + row0 * 128 + idx);
    ushort4 xb;
    xb.x = f2bf(x4.x); xb.y = f2bf(x4.y); xb.z = f2bf(x4.z); xb.w = f2bf(x4.w);
    *reinterpret_cast<ushort4*>(&Xs[r][c]) = xb;
  }
#pragma unroll
  for (int i = 0; i < 16; ++i) {
    int idx = (i * 256 + t) * 4;
    int r = idx >> 7, c = idx & 127;
    const float4 w4 = *reinterpret_cast<const float4*>(Wk + idx);
    ushort4 wb;
    wb.x = f2bf(w4.x); wb.y = f2bf(w4.y); wb.z = f2bf(w4.z); wb.w = f2bf(w4.w);
    *reinterpret_cast<ushort4*>(&Ws[r][c]) = wb;
  }
  __syncthreads();

  f32x4 acc[8];
#pragma unroll
  for (int tt = 0; tt < 8; ++tt) acc[tt] = (f32x4){0.f, 0.f, 0.f, 0.f};
#pragma unroll
  for (int c = 0; c < 4; ++c) {
    bf16x8 af = *reinterpret_cast<const bf16x8*>(&Xs[wid * 16 + ln][c * 32 + g * 8]);
#pragma unroll
    for (int tt = 0; tt < 8; ++tt) {
      bf16x8 bfr = *reinterpret_cast<const bf16x8*>(&Ws[tt * 16 + ln][c * 32 + g * 8]);
      acc[tt] = MFMA16(af, bfr, acc[tt]);
    }
  }
#pragma unroll
  for (int tt = 0; tt < 8; ++tt)
#pragma unroll
    for (int r = 0; r < 4; ++r) {
      long row = row0 + wid * 16 + g * 4 + r;
      Kout[row * 128 + tt * 16 + ln] = f2bf(acc[tt][r] + bzk[tt]);
    }

  __syncthreads();
#pragma unroll
  for (int i = 0; i < 16; ++i) {
    int idx = (i * 256 + t) * 4;
    int r = idx >> 7, c = idx & 127;
    const float4 w4 = *reinterpret_cast<const float4*>(Wv + idx);
    ushort4 wb;
    wb.x = f2bf(w4.x); wb.y = f2bf(w4.y); wb.z = f2bf(w4.z); wb.w = f2bf(w4.w);
    *reinterpret_cast<ushort4*>(&Ws[r][c]) = wb;
  }
  __syncthreads();

#pragma unroll
  for (int tt = 0; tt < 8; ++tt) acc[tt] = (f32x4){0.f, 0.f, 0.f, 0.f};
#pragma unroll
  for (int c = 0; c < 4; ++c) {
    bf16x8 af = *reinterpret_cast<const bf16x8*>(&Xs[wid * 16 + ln][c * 32 + g * 8]);
#pragma unroll
    for (int tt = 0; tt < 8; ++tt) {
      bf16x8 bfr = *reinterpret_cast<const bf16x8*>(&Ws[tt * 16 + ln][c * 32 + g * 8]);
      acc[tt] = MFMA16(af, bfr, acc[tt]);
    }
  }
#pragma unroll
  for (int tt = 0; tt < 8; ++tt)
#pragma unroll
    for (int r = 0; r < 4; ++r) {
      long row = row0 + wid * 16 + g * 4 + r;
      long bb = row >> 11, rr = row & 2047;
      Vout[(bb * 128 + tt * 16 + ln) * 2048 + rr] = f2bf(acc[tt][r] + bzv[tt]);
    }
}

// Flash attention: LDS staging restored (R15 proved direct-global is 2.7x
// worse — L1 serializes the scattered lane reads; LDS banks don't).
// NEW: each wave owns 64 q-rows as 2x32 subtiles -> each K/V LDS read feeds
// 2 MFMAs, halving the LDS-pipe load (the measured R14 bottleneck).
// Block = 4 waves x 64q = 256 q-rows; grid = 256 (1 block/CU).
// R8-proven barrier skeleton + T14 prefetch; defer-max; permlane P-exchange.
__global__ __launch_bounds__(256)
void attn_kernel(const unsigned short* __restrict__ Qg,
                 const unsigned short* __restrict__ Kg,
                 const unsigned short* __restrict__ Vtg,
                 unsigned short* __restrict__ Fg)
{
  __shared__ __align__(16) unsigned short Ks[32][136];
  __shared__ __align__(16) unsigned short Vs[128][40];

  const int t = threadIdx.x;          // 0..255
  const int lane = t & 63;
  const int q = lane & 31;
  const int hi = lane >> 5;
  const int wid = t >> 6;

  // XCD swizzle over 256 blocks: all 8 q-blocks of a batch on one XCD
  const int gbid = blockIdx.x;
  const int k_ = gbid >> 3, r_ = gbid & 7;
  const int b = r_ + 8 * (k_ >> 3);
  const int j = k_ & 7;
  const int q0 = j * 256 + wid * 64;

  const unsigned short* Qb = Qg + (long)b * 2048 * 128;
  const unsigned short* Kb = Kg + (long)b * 2048 * 128;
  const unsigned short* Vb = Vtg + (long)b * 128 * 2048;

  const int kr = t >> 4, kc = (t & 15) * 8;   // K tile [32][128]: rows kr, kr+16
  const int vc = t >> 2, ko = (t & 3) * 8;    // V^T tile [128][32]: rows vc, vc+64

  // Q fragments for both subtiles
  bf16x8 qf0[8], qf1[8];
#pragma unroll
  for (int c = 0; c < 8; ++c) {
    qf0[c] = *reinterpret_cast<const bf16x8*>(
        Qb + (long)(q0 + q) * 128 + c * 16 + hi * 8);
    qf1[c] = *reinterpret_cast<const bf16x8*>(
        Qb + (long)(q0 + 32 + q) * 128 + c * 16 + hi * 8);
  }

  f32x16 o0[4], o1[4];
#pragma unroll
  for (int dc = 0; dc < 4; ++dc)
#pragma unroll
    for (int r = 0; r < 16; ++r) { o0[dc][r] = 0.f; o1[dc][r] = 0.f; }
  float mrun0 = -1e30f, mrun1 = -1e30f;
  float lrun0 = 0.f, lrun1 = 0.f;

  // shared softmax block (subtile-generic); updates running stats + O-rescale,
  // emits the two PV A-fragments
  auto softmax_fn = [&](const f32x16& st, float& mr, float& lr, f32x16* oacc,
                        bf16x8& pav0, bf16x8& pav1) {
    float tm = st[0];
#pragma unroll
    for (int r = 1; r < 16; ++r) tm = fmaxf(tm, st[r]);
    tm = fmaxf(tm, __shfl_xor(tm, 32));
    float mcur = mr;
    if (!__all(tm <= mcur + 8.0f)) {
      float mnew = fmaxf(mcur, tm);
      float al = __builtin_amdgcn_exp2f(mcur - mnew);
      mr = mnew; mcur = mnew; lr *= al;
#pragma unroll
      for (int r = 0; r < 16; ++r) {
        float ar = __shfl(al, (r & 3) + 8 * (r >> 2) + 4 * hi);
#pragma unroll
        for (int dc = 0; dc < 4; ++dc) oacc[dc][r] *= ar;
      }
    }
    unsigned pk[8];
    float s[8];
#pragma unroll
    for (int j2 = 0; j2 < 8; ++j2) {
      float pa_ = __builtin_amdgcn_exp2f(st[2 * j2] - mcur);
      float pb_ = __builtin_amdgcn_exp2f(st[2 * j2 + 1] - mcur);
      s[j2] = pa_ + pb_;
      pk[j2] = pack2(pa_, pb_);
    }
#pragma unroll
    for (int j2 = 0; j2 < 4; ++j2) s[j2] += s[j2 + 4];
    lr += (s[0] + s[1]) + (s[2] + s[3]);
    union { unsigned u[4]; bf16x8 v; } A, B;
    swap32(pk[0], pk[2], hi, A.u[0], A.u[2]);
    swap32(pk[1], pk[3], hi, A.u[1], A.u[3]);
    swap32(pk[4], pk[6], hi, B.u[0], B.u[2]);
    swap32(pk[5], pk[7], hi, B.u[1], B.u[3]);
    pav0 = A.v; pav1 = B.v;
  };

  // prologue: issue tile 0's loads
  uint4v kreg0 = *reinterpret_cast<const uint4v*>(Kb + (long)kr * 128 + kc);
  uint4v kreg1 = *reinterpret_cast<const uint4v*>(Kb + (long)(kr + 16) * 128 + kc);
  uint4v vreg0 = *reinterpret_cast<const uint4v*>(Vb + (long)vc * 2048 + ko);
  uint4v vreg1 = *reinterpret_cast<const uint4v*>(Vb + (long)(vc + 64) * 2048 + ko);

  for (int kt = 0; kt < 64; ++kt) {
    __syncthreads();
    *reinterpret_cast<uint4v*>(&Ks[kr][kc]) = kreg0;
    *reinterpret_cast<uint4v*>(&Ks[kr + 16][kc]) = kreg1;
    *reinterpret_cast<uint4v*>(&Vs[vc][ko]) = vreg0;
    *reinterpret_cast<uint4v*>(&Vs[vc + 64][ko]) = vreg1;
    __syncthreads();

    if (kt < 63) {     // T14: issue next tile's loads now
      const int nv0 = (kt + 1) * 32;
      kreg0 = *reinterpret_cast<const uint4v*>(Kb + (long)(nv0 + kr) * 128 + kc);
      kreg1 = *reinterpret_cast<const uint4v*>(Kb + (long)(nv0 + kr + 16) * 128 + kc);
      vreg0 = *reinterpret_cast<const uint4v*>(Vb + (long)vc * 2048 + nv0 + ko);
      vreg1 = *reinterpret_cast<const uint4v*>(Vb + (long)(vc + 64) * 2048 + nv0 + ko);
    }

    // QK^T: one kf read feeds BOTH subtiles
    f32x16 st0, st1;
#pragma unroll
    for (int r = 0; r < 16; ++r) { st0[r] = 0.f; st1[r] = 0.f; }
    __builtin_amdgcn_s_setprio(1);
#pragma unroll
    for (int c = 0; c < 8; ++c) {
      bf16x8 kf = *reinterpret_cast<const bf16x8*>(&Ks[q][c * 16 + hi * 8]);
      st0 = MFMA32(kf, qf0[c], st0);
      st1 = MFMA32(kf, qf1[c], st1);
    }
    __builtin_amdgcn_s_setprio(0);

    bf16x8 paA0, paA1, paB0, paB1;
    softmax_fn(st0, mrun0, lrun0, o0, paA0, paA1);
    softmax_fn(st1, mrun1, lrun1, o1, paB0, paB1);

    // PV: one vf pair feeds BOTH subtiles
    __builtin_amdgcn_s_setprio(1);
#pragma unroll
    for (int dc = 0; dc < 4; ++dc) {
      bf16x8 vf0 = *reinterpret_cast<const bf16x8*>(&Vs[dc * 32 + q][hi * 8]);
      bf16x8 vf1 = *reinterpret_cast<const bf16x8*>(&Vs[dc * 32 + q][16 + hi * 8]);
      o0[dc] = MFMA32(paA0, vf0, o0[dc]);
      o0[dc] = MFMA32(paA1, vf1, o0[dc]);
      o1[dc] = MFMA32(paB0, vf0, o1[dc]);
      o1[dc] = MFMA32(paB1, vf1, o1[dc]);
    }
    __builtin_amdgcn_s_setprio(0);
  }

  // epilogue: both subtiles
  {
    float ltot = lrun0 + __shfl_xor(lrun0, 32);
    float inv = 1.f / ltot;
#pragma unroll
    for (int r = 0; r < 16; ++r) {
      const int qr = (r & 3) + 8 * (r >> 2) + 4 * hi;
      float invr = __shfl(inv, qr);
      long row = (long)b * 2048 + q0 + qr;
#pragma unroll
      for (int dc = 0; dc < 4; ++dc)
        Fg[row * 128 + dc * 32 + q] = f2bf(o0[dc][r] * invr);
    }
  }
  {
    float ltot = lrun1 + __shfl_xor(lrun1, 32);
    float inv = 1.f / ltot;
#pragma unroll
    for (int r = 0; r < 16; ++r) {
      const int qr = (r & 3) + 8 * (r >> 2) + 4 * hi;
      float invr = __shfl(inv, qr);
      long row = (long)b * 2048 + q0 + 32 + qr;
#pragma unroll
      for (int dc = 0; dc < 4; ++dc)
        Fg[row * 128 + dc * 32 + q] = f2bf(o1[dc][r] * invr);
    }
  }
}

extern "C" void kernel_launch(void* const* d_in, const int* in_sizes, int n_in,
                              void* d_out, int out_size, void* d_ws, size_t ws_size,
                              hipStream_t stream)
{
  (void)in_sizes; (void)n_in; (void)out_size; (void)ws_size;
  const float* smiles = (const float*)d_in[0];
  const float* image  = (const float*)d_in[1];
  const float* Wv = (const float*)d_in[2]; const float* bv = (const float*)d_in[3];
  const float* Wk = (const float*)d_in[4]; const float* bk = (const float*)d_in[5];
  const float* Wq = (const float*)d_in[6]; const float* bq = (const float*)d_in[7];
  const float* Wd = (const float*)d_in[8]; const float* bd = (const float*)d_in[9];

  unsigned short* Qw = (unsigned short*)d_ws;          // [32][2048][128] bf16
  unsigned short* Kw = Qw + 8388608;                   // [32][2048][128] bf16
  unsigned short* Vw = Kw + 8388608;                   // [32][128][2048] bf16 (V^T)
  unsigned short* Fw = Vw + 8388608;                   // [32][2048][128] bf16 fusion

  const float qscale = 1.4426950408889634f * 0.08838834764831845f;

  dim3 blk(256);
  proj_kernel<true, 0><<<dim3(1024), blk, 0, stream>>>(image, Wq, bq, Qw, qscale);
  proj_kv_kernel<<<dim3(1024), blk, 0, stream>>>(smiles, Wk, bk, Wv, bv, Kw, Vw);
  attn_kernel<<<dim3(256), blk, 0, stream>>>(Qw, Kw, Vw, Fw);
  proj_kernel<false, 2><<<dim3(1024), blk, 0, stream>>>(Fw, Wd, bd, (float*)d_out, 1.f);
}

// Round 18
// 125.974 us; speedup vs baseline: 2.1919x; 1.3509x over previous
//
#include <hip/hip_runtime.h>
#include <hip/hip_bf16.h>

typedef __attribute__((ext_vector_type(4))) float f32x4;
typedef __attribute__((ext_vector_type(16))) float f32x16;
typedef __attribute__((ext_vector_type(8))) short bf16x8;
typedef __attribute__((ext_vector_type(4))) unsigned int uint4v;
typedef __attribute__((ext_vector_type(2))) unsigned int uint2v;

#define MFMA16(a, b, c) __builtin_amdgcn_mfma_f32_16x16x32_bf16(a, b, c, 0, 0, 0)
#define MFMA32(a, b, c) __builtin_amdgcn_mfma_f32_32x32x16_bf16(a, b, c, 0, 0, 0)

__device__ __forceinline__ unsigned short f2bf(float f) {
  union { float f; unsigned u; } v; v.f = f;
  unsigned r = v.u + 0x7fffu + ((v.u >> 16) & 1u);
  return (unsigned short)(r >> 16);
}
__device__ __forceinline__ unsigned pack2(float a, float b) {
  union { __hip_bfloat162 h2; unsigned u; } cv;
  cv.h2 = __hip_bfloat162(__float2bfloat16(a), __float2bfloat16(b));
  return cv.u;
}

// cross-half exchange (validated R10-R14)
__device__ __forceinline__ void swap32(unsigned a, unsigned b, int hi,
                                       unsigned& ox, unsigned& oy) {
#if __has_builtin(__builtin_amdgcn_permlane32_swap)
  uint2v r = __builtin_amdgcn_permlane32_swap(a, b, false, false);
  ox = r[0]; oy = r[1];
#else
  unsigned sb = __shfl_xor(b, 32);
  unsigned sa = __shfl_xor(a, 32);
  ox = hi ? sb : a;
  oy = hi ? b : sa;
#endif
}

// y = x @ W^T + b, M=65536 rows, N=K=128. (used for final D-projection)
// OUT_MODE: 0 = bf16 [M][128]; 2 = f32 [M][128]
template<bool IN_F32, int OUT_MODE>
__global__ __launch_bounds__(256)
void proj_kernel(const void* __restrict__ xin, const float* __restrict__ W,
                 const float* __restrict__ bias, void* __restrict__ yout,
                 float scale)
{
  __shared__ __align__(16) unsigned short Ws[128][136];
  __shared__ __align__(16) unsigned short Xs[64][136];
  const int t = threadIdx.x;
  const int wid = t >> 6;
  const int lane = t & 63;
  const int ln = lane & 15, g = lane >> 4;
  const long row0 = (long)blockIdx.x * 64;

  float bz[8];
#pragma unroll
  for (int tt = 0; tt < 8; ++tt) bz[tt] = bias[tt * 16 + ln];

#pragma unroll
  for (int i = 0; i < 16; ++i) {
    int idx = (i * 256 + t) * 4;
    int r = idx >> 7, c = idx & 127;
    const float4 w4 = *reinterpret_cast<const float4*>(W + idx);
    ushort4 wb;
    wb.x = f2bf(w4.x); wb.y = f2bf(w4.y); wb.z = f2bf(w4.z); wb.w = f2bf(w4.w);
    *reinterpret_cast<ushort4*>(&Ws[r][c]) = wb;
  }
  if (IN_F32) {
    const float* x = (const float*)xin;
#pragma unroll
    for (int i = 0; i < 8; ++i) {
      int idx = (i * 256 + t) * 4;
      int r = idx >> 7, c = idx & 127;
      const float4 x4 = *reinterpret_cast<const float4*>(x + row0 * 128 + idx);
      ushort4 xb;
      xb.x = f2bf(x4.x); xb.y = f2bf(x4.y); xb.z = f2bf(x4.z); xb.w = f2bf(x4.w);
      *reinterpret_cast<ushort4*>(&Xs[r][c]) = xb;
    }
  } else {
    const unsigned short* x = (const unsigned short*)xin;
#pragma unroll
    for (int i = 0; i < 4; ++i) {
      int idx = (i * 256 + t) * 8;
      int r = idx >> 7, c = idx & 127;
      *reinterpret_cast<uint4v*>(&Xs[r][c]) =
          *reinterpret_cast<const uint4v*>(x + row0 * 128 + idx);
    }
  }
  __syncthreads();

  f32x4 acc[8];
#pragma unroll
  for (int tt = 0; tt < 8; ++tt) acc[tt] = (f32x4){0.f, 0.f, 0.f, 0.f};

#pragma unroll
  for (int c = 0; c < 4; ++c) {
    bf16x8 af = *reinterpret_cast<const bf16x8*>(&Xs[wid * 16 + ln][c * 32 + g * 8]);
#pragma unroll
    for (int tt = 0; tt < 8; ++tt) {
      bf16x8 bfr = *reinterpret_cast<const bf16x8*>(&Ws[tt * 16 + ln][c * 32 + g * 8]);
      acc[tt] = MFMA16(af, bfr, acc[tt]);
    }
  }

#pragma unroll
  for (int tt = 0; tt < 8; ++tt) {
#pragma unroll
    for (int r = 0; r < 4; ++r) {
      long row = row0 + wid * 16 + g * 4 + r;
      int col = tt * 16 + ln;
      float val = (acc[tt][r] + bz[tt]) * scale;
      if (OUT_MODE == 2) {
        ((float*)yout)[row * 128 + col] = val;
      } else {
        ((unsigned short*)yout)[row * 128 + col] = f2bf(val);
      }
    }
  }
}

// Fused Q + K + V projections in ONE dispatch (2048 blocks):
// blocks 0..1023: Q = image@Wq^T + bq (scaled, bf16 row-major)
// blocks 1024..2047: K and V from smiles (X staged once, two weight phases)
__global__ __launch_bounds__(256)
void proj_qkv_kernel(const float* __restrict__ image,
                     const float* __restrict__ Wq, const float* __restrict__ bq,
                     float qscale,
                     const float* __restrict__ smiles,
                     const float* __restrict__ Wk, const float* __restrict__ bk,
                     const float* __restrict__ Wv, const float* __restrict__ bv,
                     unsigned short* __restrict__ Qout,
                     unsigned short* __restrict__ Kout,
                     unsigned short* __restrict__ Vout)
{
  __shared__ __align__(16) unsigned short Ws[128][136];
  __shared__ __align__(16) unsigned short Xs[64][136];
  const int t = threadIdx.x;
  const int wid = t >> 6;
  const int lane = t & 63;
  const int ln = lane & 15, g = lane >> 4;
  const bool isQ = blockIdx.x < 1024;
  const long row0 = (long)(isQ ? blockIdx.x : blockIdx.x - 1024) * 64;
  const float* x = isQ ? image : smiles;

  // stage X tile (shared by all phases)
#pragma unroll
  for (int i = 0; i < 8; ++i) {
    int idx = (i * 256 + t) * 4;
    int r = idx >> 7, c = idx & 127;
    const float4 x4 = *reinterpret_cast<const float4*>(x + row0 * 128 + idx);
    ushort4 xb;
    xb.x = f2bf(x4.x); xb.y = f2bf(x4.y); xb.z = f2bf(x4.z); xb.w = f2bf(x4.w);
    *reinterpret_cast<ushort4*>(&Xs[r][c]) = xb;
  }

  const float* W1 = isQ ? Wq : Wk;
  const float* b1 = isQ ? bq : bk;
  float bz[8];
#pragma unroll
  for (int tt = 0; tt < 8; ++tt) bz[tt] = b1[tt * 16 + ln];

#pragma unroll
  for (int i = 0; i < 16; ++i) {
    int idx = (i * 256 + t) * 4;
    int r = idx >> 7, c = idx & 127;
    const float4 w4 = *reinterpret_cast<const float4*>(W1 + idx);
    ushort4 wb;
    wb.x = f2bf(w4.x); wb.y = f2bf(w4.y); wb.z = f2bf(w4.z); wb.w = f2bf(w4.w);
    *reinterpret_cast<ushort4*>(&Ws[r][c]) = wb;
  }
  __syncthreads();

  f32x4 acc[8];
#pragma unroll
  for (int tt = 0; tt < 8; ++tt) acc[tt] = (f32x4){0.f, 0.f, 0.f, 0.f};
#pragma unroll
  for (int c = 0; c < 4; ++c) {
    bf16x8 af = *reinterpret_cast<const bf16x8*>(&Xs[wid * 16 + ln][c * 32 + g * 8]);
#pragma unroll
    for (int tt = 0; tt < 8; ++tt) {
      bf16x8 bfr = *reinterpret_cast<const bf16x8*>(&Ws[tt * 16 + ln][c * 32 + g * 8]);
      acc[tt] = MFMA16(af, bfr, acc[tt]);
    }
  }

  if (isQ) {
#pragma unroll
    for (int tt = 0; tt < 8; ++tt)
#pragma unroll
      for (int r = 0; r < 4; ++r) {
        long row = row0 + wid * 16 + g * 4 + r;
        Qout[row * 128 + tt * 16 + ln] = f2bf((acc[tt][r] + bz[tt]) * qscale);
      }
    return;
  }

  // K write
#pragma unroll
  for (int tt = 0; tt < 8; ++tt)
#pragma unroll
    for (int r = 0; r < 4; ++r) {
      long row = row0 + wid * 16 + g * 4 + r;
      Kout[row * 128 + tt * 16 + ln] = f2bf(acc[tt][r] + bz[tt]);
    }

  // V phase: restage Ws with Wv
  __syncthreads();
#pragma unroll
  for (int i = 0; i < 16; ++i) {
    int idx = (i * 256 + t) * 4;
    int r = idx >> 7, c = idx & 127;
    const float4 w4 = *reinterpret_cast<const float4*>(Wv + idx);
    ushort4 wb;
    wb.x = f2bf(w4.x); wb.y = f2bf(w4.y); wb.z = f2bf(w4.z); wb.w = f2bf(w4.w);
    *reinterpret_cast<ushort4*>(&Ws[r][c]) = wb;
  }
  __syncthreads();

  float bzv[8];
#pragma unroll
  for (int tt = 0; tt < 8; ++tt) bzv[tt] = bv[tt * 16 + ln];
#pragma unroll
  for (int tt = 0; tt < 8; ++tt) acc[tt] = (f32x4){0.f, 0.f, 0.f, 0.f};
#pragma unroll
  for (int c = 0; c < 4; ++c) {
    bf16x8 af = *reinterpret_cast<const bf16x8*>(&Xs[wid * 16 + ln][c * 32 + g * 8]);
#pragma unroll
    for (int tt = 0; tt < 8; ++tt) {
      bf16x8 bfr = *reinterpret_cast<const bf16x8*>(&Ws[tt * 16 + ln][c * 32 + g * 8]);
      acc[tt] = MFMA16(af, bfr, acc[tt]);
    }
  }
#pragma unroll
  for (int tt = 0; tt < 8; ++tt)
#pragma unroll
    for (int r = 0; r < 4; ++r) {
      long row = row0 + wid * 16 + g * 4 + r;
      long bb = row >> 11, rr = row & 2047;
      Vout[(bb * 128 + tt * 16 + ln) * 2048 + rr] = f2bf(acc[tt][r] + bzv[tt]);
    }
}

// Flash attention (R14 loop body) + single-barrier DOUBLE-BUFFER:
// between consecutive __syncthreads, reads touch buf[kt&1] and writes touch
// buf[kt&1 ^ 1] — disjoint, so one barrier per iteration is provably race-free
// (no wave can be >1 barrier ahead). T14 prefetch now runs 2 tiles ahead.
__global__ __launch_bounds__(256)
void attn_kernel(const unsigned short* __restrict__ Qg,
                 const unsigned short* __restrict__ Kg,
                 const unsigned short* __restrict__ Vtg,
                 unsigned short* __restrict__ Fg)
{
  __shared__ __align__(16) unsigned short Ks[2][32][136];
  __shared__ __align__(16) unsigned short Vs[2][128][40];

  const int t = threadIdx.x;          // 0..255
  const int lane = t & 63;
  const int q = lane & 31;
  const int hi = lane >> 5;
  const int wid = t >> 6;

  // XCD swizzle (R13/R14-proven): all 16 q-blocks of a batch on one XCD
  const int gbid = blockIdx.x;
  const int k_ = gbid >> 3, r_ = gbid & 7;
  const int b = r_ + 8 * (k_ >> 4);
  const int j = k_ & 15;
  const int q0 = j * 128 + wid * 32;

  const unsigned short* Qb = Qg + (long)b * 2048 * 128;
  const unsigned short* Kb = Kg + (long)b * 2048 * 128;
  const unsigned short* Vb = Vtg + (long)b * 128 * 2048;

  const int kr = t >> 4, kc = (t & 15) * 8;   // K tile [32][128]: rows kr, kr+16
  const int vc = t >> 2, ko = (t & 3) * 8;    // V^T tile [128][32]: rows vc, vc+64

  bf16x8 qf[8];
#pragma unroll
  for (int c = 0; c < 8; ++c)
    qf[c] = *reinterpret_cast<const bf16x8*>(
        Qb + (long)(q0 + q) * 128 + c * 16 + hi * 8);

  f32x16 o[4];
#pragma unroll
  for (int dc = 0; dc < 4; ++dc)
#pragma unroll
    for (int r = 0; r < 16; ++r) o[dc][r] = 0.f;
  float mrun = -1e30f;
  float lrun = 0.f;

  // prologue: tile 0 -> buf0; then issue tile 1's loads (T14)
  uint4v kreg0 = *reinterpret_cast<const uint4v*>(Kb + (long)kr * 128 + kc);
  uint4v kreg1 = *reinterpret_cast<const uint4v*>(Kb + (long)(kr + 16) * 128 + kc);
  uint4v vreg0 = *reinterpret_cast<const uint4v*>(Vb + (long)vc * 2048 + ko);
  uint4v vreg1 = *reinterpret_cast<const uint4v*>(Vb + (long)(vc + 64) * 2048 + ko);
  *reinterpret_cast<uint4v*>(&Ks[0][kr][kc]) = kreg0;
  *reinterpret_cast<uint4v*>(&Ks[0][kr + 16][kc]) = kreg1;
  *reinterpret_cast<uint4v*>(&Vs[0][vc][ko]) = vreg0;
  *reinterpret_cast<uint4v*>(&Vs[0][vc + 64][ko]) = vreg1;
  kreg0 = *reinterpret_cast<const uint4v*>(Kb + (long)(32 + kr) * 128 + kc);
  kreg1 = *reinterpret_cast<const uint4v*>(Kb + (long)(32 + kr + 16) * 128 + kc);
  vreg0 = *reinterpret_cast<const uint4v*>(Vb + (long)vc * 2048 + 32 + ko);
  vreg1 = *reinterpret_cast<const uint4v*>(Vb + (long)(vc + 64) * 2048 + 32 + ko);
  __syncthreads();

  for (int kt = 0; kt < 64; ++kt) {
    const int cur = kt & 1;

    // publish tile kt+1 into the other buffer (disjoint from this iter's reads)
    if (kt < 63) {
      const int nb = cur ^ 1;
      *reinterpret_cast<uint4v*>(&Ks[nb][kr][kc]) = kreg0;
      *reinterpret_cast<uint4v*>(&Ks[nb][kr + 16][kc]) = kreg1;
      *reinterpret_cast<uint4v*>(&Vs[nb][vc][ko]) = vreg0;
      *reinterpret_cast<uint4v*>(&Vs[nb][vc + 64][ko]) = vreg1;
      if (kt < 62) {   // issue tile kt+2's loads — a full iteration of slack
        const int nv0 = (kt + 2) * 32;
        kreg0 = *reinterpret_cast<const uint4v*>(Kb + (long)(nv0 + kr) * 128 + kc);
        kreg1 = *reinterpret_cast<const uint4v*>(Kb + (long)(nv0 + kr + 16) * 128 + kc);
        vreg0 = *reinterpret_cast<const uint4v*>(Vb + (long)vc * 2048 + nv0 + ko);
        vreg1 = *reinterpret_cast<const uint4v*>(Vb + (long)(vc + 64) * 2048 + nv0 + ko);
      }
    }

    // QK^T from buf[cur]
    f32x16 st;
#pragma unroll
    for (int r = 0; r < 16; ++r) st[r] = 0.f;
    __builtin_amdgcn_s_setprio(1);
#pragma unroll
    for (int c = 0; c < 8; ++c) {
      bf16x8 kf = *reinterpret_cast<const bf16x8*>(&Ks[cur][q][c * 16 + hi * 8]);
      st = MFMA32(kf, qf[c], st);
    }
    __builtin_amdgcn_s_setprio(0);

    float tm = st[0];
#pragma unroll
    for (int r = 1; r < 16; ++r) tm = fmaxf(tm, st[r]);
    tm = fmaxf(tm, __shfl_xor(tm, 32));

    float mcur = mrun;
    if (!__all(tm <= mcur + 8.0f)) {
      float mnew = fmaxf(mcur, tm);
      float al = __builtin_amdgcn_exp2f(mcur - mnew);
      mrun = mnew;
      mcur = mnew;
      lrun *= al;
#pragma unroll
      for (int r = 0; r < 16; ++r) {
        float ar = __shfl(al, (r & 3) + 8 * (r >> 2) + 4 * hi);
#pragma unroll
        for (int dc = 0; dc < 4; ++dc) o[dc][r] *= ar;
      }
    }

    unsigned pk[8];
    float s[8];
#pragma unroll
    for (int j2 = 0; j2 < 8; ++j2) {
      float pa_ = __builtin_amdgcn_exp2f(st[2 * j2] - mcur);
      float pb_ = __builtin_amdgcn_exp2f(st[2 * j2 + 1] - mcur);
      s[j2] = pa_ + pb_;
      pk[j2] = pack2(pa_, pb_);
    }
#pragma unroll
    for (int j2 = 0; j2 < 4; ++j2) s[j2] += s[j2 + 4];
    lrun += (s[0] + s[1]) + (s[2] + s[3]);

    union { unsigned u[4]; bf16x8 v; } pa0, pa1;
    swap32(pk[0], pk[2], hi, pa0.u[0], pa0.u[2]);
    swap32(pk[1], pk[3], hi, pa0.u[1], pa0.u[3]);
    swap32(pk[4], pk[6], hi, pa1.u[0], pa1.u[2]);
    swap32(pk[5], pk[7], hi, pa1.u[1], pa1.u[3]);

    // PV from buf[cur]
    __builtin_amdgcn_s_setprio(1);
#pragma unroll
    for (int dc = 0; dc < 4; ++dc) {
      bf16x8 vf0 = *reinterpret_cast<const bf16x8*>(&Vs[cur][dc * 32 + q][hi * 8]);
      bf16x8 vf1 = *reinterpret_cast<const bf16x8*>(&Vs[cur][dc * 32 + q][16 + hi * 8]);
      o[dc] = MFMA32(pa0.v, vf0, o[dc]);
      o[dc] = MFMA32(pa1.v, vf1, o[dc]);
    }
    __builtin_amdgcn_s_setprio(0);

    __syncthreads();   // single barrier per iteration
  }

  float ltot = lrun + __shfl_xor(lrun, 32);
  float inv = 1.f / ltot;
#pragma unroll
  for (int r = 0; r < 16; ++r) {
    const int qr = (r & 3) + 8 * (r >> 2) + 4 * hi;
    float invr = __shfl(inv, qr);
    long row = (long)b * 2048 + q0 + qr;
#pragma unroll
    for (int dc = 0; dc < 4; ++dc)
      Fg[row * 128 + dc * 32 + q] = f2bf(o[dc][r] * invr);
  }
}

extern "C" void kernel_launch(void* const* d_in, const int* in_sizes, int n_in,
                              void* d_out, int out_size, void* d_ws, size_t ws_size,
                              hipStream_t stream)
{
  (void)in_sizes; (void)n_in; (void)out_size; (void)ws_size;
  const float* smiles = (const float*)d_in[0];
  const float* image  = (const float*)d_in[1];
  const float* Wv = (const float*)d_in[2]; const float* bv = (const float*)d_in[3];
  const float* Wk = (const float*)d_in[4]; const float* bk = (const float*)d_in[5];
  const float* Wq = (const float*)d_in[6]; const float* bq = (const float*)d_in[7];
  const float* Wd = (const float*)d_in[8]; const float* bd = (const float*)d_in[9];

  unsigned short* Qw = (unsigned short*)d_ws;          // [32][2048][128] bf16
  unsigned short* Kw = Qw + 8388608;                   // [32][2048][128] bf16
  unsigned short* Vw = Kw + 8388608;                   // [32][128][2048] bf16 (V^T)
  unsigned short* Fw = Vw + 8388608;                   // [32][2048][128] bf16 fusion

  const float qscale = 1.4426950408889634f * 0.08838834764831845f;

  dim3 blk(256);
  proj_qkv_kernel<<<dim3(2048), blk, 0, stream>>>(image, Wq, bq, qscale,
                                                  smiles, Wk, bk, Wv, bv,
                                                  Qw, Kw, Vw);
  attn_kernel<<<dim3(512), blk, 0, stream>>>(Qw, Kw, Vw, Fw);
  proj_kernel<false, 2><<<dim3(1024), blk, 0, stream>>>(Fw, Wd, bd, (float*)d_out, 1.f);
}

// Round 19
// 118.598 us; speedup vs baseline: 2.3282x; 1.0622x over previous
//
#include <hip/hip_runtime.h>
#include <hip/hip_bf16.h>

typedef __attribute__((ext_vector_type(4))) float f32x4;
typedef __attribute__((ext_vector_type(16))) float f32x16;
typedef __attribute__((ext_vector_type(8))) short bf16x8;
typedef __attribute__((ext_vector_type(4))) unsigned int uint4v;
typedef __attribute__((ext_vector_type(2))) unsigned int uint2v;

#define MFMA16(a, b, c) __builtin_amdgcn_mfma_f32_16x16x32_bf16(a, b, c, 0, 0, 0)
#define MFMA32(a, b, c) __builtin_amdgcn_mfma_f32_32x32x16_bf16(a, b, c, 0, 0, 0)

__device__ __forceinline__ unsigned short f2bf(float f) {
  union { float f; unsigned u; } v; v.f = f;
  unsigned r = v.u + 0x7fffu + ((v.u >> 16) & 1u);
  return (unsigned short)(r >> 16);
}
__device__ __forceinline__ unsigned pack2(float a, float b) {
  union { __hip_bfloat162 h2; unsigned u; } cv;
  cv.h2 = __hip_bfloat162(__float2bfloat16(a), __float2bfloat16(b));
  return cv.u;
}

// cross-half exchange (validated R10-R18)
__device__ __forceinline__ void swap32(unsigned a, unsigned b, int hi,
                                       unsigned& ox, unsigned& oy) {
#if __has_builtin(__builtin_amdgcn_permlane32_swap)
  uint2v r = __builtin_amdgcn_permlane32_swap(a, b, false, false);
  ox = r[0]; oy = r[1];
#else
  unsigned sb = __shfl_xor(b, 32);
  unsigned sa = __shfl_xor(a, 32);
  ox = hi ? sb : a;
  oy = hi ? b : sa;
#endif
}

// Fused Q + K + V projections in ONE dispatch (2048 blocks) — R18-proven.
__global__ __launch_bounds__(256)
void proj_qkv_kernel(const float* __restrict__ image,
                     const float* __restrict__ Wq, const float* __restrict__ bq,
                     float qscale,
                     const float* __restrict__ smiles,
                     const float* __restrict__ Wk, const float* __restrict__ bk,
                     const float* __restrict__ Wv, const float* __restrict__ bv,
                     unsigned short* __restrict__ Qout,
                     unsigned short* __restrict__ Kout,
                     unsigned short* __restrict__ Vout)
{
  __shared__ __align__(16) unsigned short Ws[128][136];
  __shared__ __align__(16) unsigned short Xs[64][136];
  const int t = threadIdx.x;
  const int wid = t >> 6;
  const int lane = t & 63;
  const int ln = lane & 15, g = lane >> 4;
  const bool isQ = blockIdx.x < 1024;
  const long row0 = (long)(isQ ? blockIdx.x : blockIdx.x - 1024) * 64;
  const float* x = isQ ? image : smiles;

#pragma unroll
  for (int i = 0; i < 8; ++i) {
    int idx = (i * 256 + t) * 4;
    int r = idx >> 7, c = idx & 127;
    const float4 x4 = *reinterpret_cast<const float4*>(x + row0 * 128 + idx);
    ushort4 xb;
    xb.x = f2bf(x4.x); xb.y = f2bf(x4.y); xb.z = f2bf(x4.z); xb.w = f2bf(x4.w);
    *reinterpret_cast<ushort4*>(&Xs[r][c]) = xb;
  }

  const float* W1 = isQ ? Wq : Wk;
  const float* b1 = isQ ? bq : bk;
  float bz[8];
#pragma unroll
  for (int tt = 0; tt < 8; ++tt) bz[tt] = b1[tt * 16 + ln];

#pragma unroll
  for (int i = 0; i < 16; ++i) {
    int idx = (i * 256 + t) * 4;
    int r = idx >> 7, c = idx & 127;
    const float4 w4 = *reinterpret_cast<const float4*>(W1 + idx);
    ushort4 wb;
    wb.x = f2bf(w4.x); wb.y = f2bf(w4.y); wb.z = f2bf(w4.z); wb.w = f2bf(w4.w);
    *reinterpret_cast<ushort4*>(&Ws[r][c]) = wb;
  }
  __syncthreads();

  f32x4 acc[8];
#pragma unroll
  for (int tt = 0; tt < 8; ++tt) acc[tt] = (f32x4){0.f, 0.f, 0.f, 0.f};
#pragma unroll
  for (int c = 0; c < 4; ++c) {
    bf16x8 af = *reinterpret_cast<const bf16x8*>(&Xs[wid * 16 + ln][c * 32 + g * 8]);
#pragma unroll
    for (int tt = 0; tt < 8; ++tt) {
      bf16x8 bfr = *reinterpret_cast<const bf16x8*>(&Ws[tt * 16 + ln][c * 32 + g * 8]);
      acc[tt] = MFMA16(af, bfr, acc[tt]);
    }
  }

  if (isQ) {
#pragma unroll
    for (int tt = 0; tt < 8; ++tt)
#pragma unroll
      for (int r = 0; r < 4; ++r) {
        long row = row0 + wid * 16 + g * 4 + r;
        Qout[row * 128 + tt * 16 + ln] = f2bf((acc[tt][r] + bz[tt]) * qscale);
      }
    return;
  }

#pragma unroll
  for (int tt = 0; tt < 8; ++tt)
#pragma unroll
    for (int r = 0; r < 4; ++r) {
      long row = row0 + wid * 16 + g * 4 + r;
      Kout[row * 128 + tt * 16 + ln] = f2bf(acc[tt][r] + bz[tt]);
    }

  __syncthreads();
#pragma unroll
  for (int i = 0; i < 16; ++i) {
    int idx = (i * 256 + t) * 4;
    int r = idx >> 7, c = idx & 127;
    const float4 w4 = *reinterpret_cast<const float4*>(Wv + idx);
    ushort4 wb;
    wb.x = f2bf(w4.x); wb.y = f2bf(w4.y); wb.z = f2bf(w4.z); wb.w = f2bf(w4.w);
    *reinterpret_cast<ushort4*>(&Ws[r][c]) = wb;
  }
  __syncthreads();

  float bzv[8];
#pragma unroll
  for (int tt = 0; tt < 8; ++tt) bzv[tt] = bv[tt * 16 + ln];
#pragma unroll
  for (int tt = 0; tt < 8; ++tt) acc[tt] = (f32x4){0.f, 0.f, 0.f, 0.f};
#pragma unroll
  for (int c = 0; c < 4; ++c) {
    bf16x8 af = *reinterpret_cast<const bf16x8*>(&Xs[wid * 16 + ln][c * 32 + g * 8]);
#pragma unroll
    for (int tt = 0; tt < 8; ++tt) {
      bf16x8 bfr = *reinterpret_cast<const bf16x8*>(&Ws[tt * 16 + ln][c * 32 + g * 8]);
      acc[tt] = MFMA16(af, bfr, acc[tt]);
    }
  }
#pragma unroll
  for (int tt = 0; tt < 8; ++tt)
#pragma unroll
    for (int r = 0; r < 4; ++r) {
      long row = row0 + wid * 16 + g * 4 + r;
      long bb = row >> 11, rr = row & 2047;
      Vout[(bb * 128 + tt * 16 + ln) * 2048 + rr] = f2bf(acc[tt][r] + bzv[tt]);
    }
}

// Flash attention (R18 single-barrier dbuf loop, unchanged) + FUSED output
// projection epilogue: after the KV loop, the K/V dbuf LDS is reused to stage
// Wd (bf16) and the per-wave O tiles (transposed), then 32 MFMA32/wave compute
// out = O@Wd^T + bd, stored f32 directly. Removes the 3rd dispatch + Fw I/O.
__global__ __launch_bounds__(256)
void attn_kernel(const unsigned short* __restrict__ Qg,
                 const unsigned short* __restrict__ Kg,
                 const unsigned short* __restrict__ Vtg,
                 const float* __restrict__ Wd,
                 const float* __restrict__ bd,
                 float* __restrict__ Out)
{
  // union'd LDS: main loop = Ks[2][32][136] (17408 B) + Vs[2][128][40] (20480 B)
  // epilogue   = Wds[128][136] (34816 B) + per-wave Os[32][136] (4x8704 B)
  __shared__ __align__(16) unsigned char smem[69632];
  auto Ks = reinterpret_cast<unsigned short (*)[32][136]>(smem);
  auto Vs = reinterpret_cast<unsigned short (*)[128][40]>(smem + 17408);

  const int t = threadIdx.x;          // 0..255
  const int lane = t & 63;
  const int q = lane & 31;
  const int hi = lane >> 5;
  const int wid = t >> 6;

  // XCD swizzle (R13/R14-proven): all 16 q-blocks of a batch on one XCD
  const int gbid = blockIdx.x;
  const int k_ = gbid >> 3, r_ = gbid & 7;
  const int b = r_ + 8 * (k_ >> 4);
  const int j = k_ & 15;
  const int q0 = j * 128 + wid * 32;

  const unsigned short* Qb = Qg + (long)b * 2048 * 128;
  const unsigned short* Kb = Kg + (long)b * 2048 * 128;
  const unsigned short* Vb = Vtg + (long)b * 128 * 2048;

  const int kr = t >> 4, kc = (t & 15) * 8;   // K tile [32][128]: rows kr, kr+16
  const int vc = t >> 2, ko = (t & 3) * 8;    // V^T tile [128][32]: rows vc, vc+64

  bf16x8 qf[8];
#pragma unroll
  for (int c = 0; c < 8; ++c)
    qf[c] = *reinterpret_cast<const bf16x8*>(
        Qb + (long)(q0 + q) * 128 + c * 16 + hi * 8);

  f32x16 o[4];
#pragma unroll
  for (int dc = 0; dc < 4; ++dc)
#pragma unroll
    for (int r = 0; r < 16; ++r) o[dc][r] = 0.f;
  float mrun = -1e30f;
  float lrun = 0.f;

  // prologue: tile 0 -> buf0; then issue tile 1's loads (T14)
  uint4v kreg0 = *reinterpret_cast<const uint4v*>(Kb + (long)kr * 128 + kc);
  uint4v kreg1 = *reinterpret_cast<const uint4v*>(Kb + (long)(kr + 16) * 128 + kc);
  uint4v vreg0 = *reinterpret_cast<const uint4v*>(Vb + (long)vc * 2048 + ko);
  uint4v vreg1 = *reinterpret_cast<const uint4v*>(Vb + (long)(vc + 64) * 2048 + ko);
  *reinterpret_cast<uint4v*>(&Ks[0][kr][kc]) = kreg0;
  *reinterpret_cast<uint4v*>(&Ks[0][kr + 16][kc]) = kreg1;
  *reinterpret_cast<uint4v*>(&Vs[0][vc][ko]) = vreg0;
  *reinterpret_cast<uint4v*>(&Vs[0][vc + 64][ko]) = vreg1;
  kreg0 = *reinterpret_cast<const uint4v*>(Kb + (long)(32 + kr) * 128 + kc);
  kreg1 = *reinterpret_cast<const uint4v*>(Kb + (long)(32 + kr + 16) * 128 + kc);
  vreg0 = *reinterpret_cast<const uint4v*>(Vb + (long)vc * 2048 + 32 + ko);
  vreg1 = *reinterpret_cast<const uint4v*>(Vb + (long)(vc + 64) * 2048 + 32 + ko);
  __syncthreads();

  for (int kt = 0; kt < 64; ++kt) {
    const int cur = kt & 1;

    if (kt < 63) {
      const int nb = cur ^ 1;
      *reinterpret_cast<uint4v*>(&Ks[nb][kr][kc]) = kreg0;
      *reinterpret_cast<uint4v*>(&Ks[nb][kr + 16][kc]) = kreg1;
      *reinterpret_cast<uint4v*>(&Vs[nb][vc][ko]) = vreg0;
      *reinterpret_cast<uint4v*>(&Vs[nb][vc + 64][ko]) = vreg1;
      if (kt < 62) {
        const int nv0 = (kt + 2) * 32;
        kreg0 = *reinterpret_cast<const uint4v*>(Kb + (long)(nv0 + kr) * 128 + kc);
        kreg1 = *reinterpret_cast<const uint4v*>(Kb + (long)(nv0 + kr + 16) * 128 + kc);
        vreg0 = *reinterpret_cast<const uint4v*>(Vb + (long)vc * 2048 + nv0 + ko);
        vreg1 = *reinterpret_cast<const uint4v*>(Vb + (long)(vc + 64) * 2048 + nv0 + ko);
      }
    }

    f32x16 st;
#pragma unroll
    for (int r = 0; r < 16; ++r) st[r] = 0.f;
    __builtin_amdgcn_s_setprio(1);
#pragma unroll
    for (int c = 0; c < 8; ++c) {
      bf16x8 kf = *reinterpret_cast<const bf16x8*>(&Ks[cur][q][c * 16 + hi * 8]);
      st = MFMA32(kf, qf[c], st);
    }
    __builtin_amdgcn_s_setprio(0);

    float tm = st[0];
#pragma unroll
    for (int r = 1; r < 16; ++r) tm = fmaxf(tm, st[r]);
    tm = fmaxf(tm, __shfl_xor(tm, 32));

    float mcur = mrun;
    if (!__all(tm <= mcur + 8.0f)) {
      float mnew = fmaxf(mcur, tm);
      float al = __builtin_amdgcn_exp2f(mcur - mnew);
      mrun = mnew;
      mcur = mnew;
      lrun *= al;
#pragma unroll
      for (int r = 0; r < 16; ++r) {
        float ar = __shfl(al, (r & 3) + 8 * (r >> 2) + 4 * hi);
#pragma unroll
        for (int dc = 0; dc < 4; ++dc) o[dc][r] *= ar;
      }
    }

    unsigned pk[8];
    float s[8];
#pragma unroll
    for (int j2 = 0; j2 < 8; ++j2) {
      float pa_ = __builtin_amdgcn_exp2f(st[2 * j2] - mcur);
      float pb_ = __builtin_amdgcn_exp2f(st[2 * j2 + 1] - mcur);
      s[j2] = pa_ + pb_;
      pk[j2] = pack2(pa_, pb_);
    }
#pragma unroll
    for (int j2 = 0; j2 < 4; ++j2) s[j2] += s[j2 + 4];
    lrun += (s[0] + s[1]) + (s[2] + s[3]);

    union { unsigned u[4]; bf16x8 v; } pa0, pa1;
    swap32(pk[0], pk[2], hi, pa0.u[0], pa0.u[2]);
    swap32(pk[1], pk[3], hi, pa0.u[1], pa0.u[3]);
    swap32(pk[4], pk[6], hi, pa1.u[0], pa1.u[2]);
    swap32(pk[5], pk[7], hi, pa1.u[1], pa1.u[3]);

    __builtin_amdgcn_s_setprio(1);
#pragma unroll
    for (int dc = 0; dc < 4; ++dc) {
      bf16x8 vf0 = *reinterpret_cast<const bf16x8*>(&Vs[cur][dc * 32 + q][hi * 8]);
      bf16x8 vf1 = *reinterpret_cast<const bf16x8*>(&Vs[cur][dc * 32 + q][16 + hi * 8]);
      o[dc] = MFMA32(pa0.v, vf0, o[dc]);
      o[dc] = MFMA32(pa1.v, vf1, o[dc]);
    }
    __builtin_amdgcn_s_setprio(0);

    __syncthreads();   // single barrier per iteration
  }

  // ---------- fused output projection: out = O @ Wd^T + bd ----------
  // (the loop's final __syncthreads guarantees all waves are done with K/V LDS)
  auto Wds = reinterpret_cast<unsigned short (*)[136]>(smem);
  auto Os  = reinterpret_cast<unsigned short (*)[136]>(smem + 34816 + wid * 8704);

  // stage Wd -> bf16 LDS [128][136] (all 256 threads cooperatively)
#pragma unroll
  for (int i = 0; i < 16; ++i) {
    int idx = (i * 256 + t) * 4;
    int r = idx >> 7, c = idx & 127;
    const float4 w4 = *reinterpret_cast<const float4*>(Wd + idx);
    ushort4 wb;
    wb.x = f2bf(w4.x); wb.y = f2bf(w4.y); wb.z = f2bf(w4.z); wb.w = f2bf(w4.w);
    *reinterpret_cast<ushort4*>(&Wds[r][c]) = wb;
  }

  // write normalized O (bf16) transposed into per-wave Os[32 q][128 d]
  float ltot = lrun + __shfl_xor(lrun, 32);
  float inv = 1.f / ltot;     // valid for row q = lane&31
#pragma unroll
  for (int r = 0; r < 16; ++r) {
    const int qr = (r & 3) + 8 * (r >> 2) + 4 * hi;
    float invr = __shfl(inv, qr);
#pragma unroll
    for (int dc = 0; dc < 4; ++dc)
      Os[qr][dc * 32 + q] = f2bf(o[dc][r] * invr);
  }
  __syncthreads();

  // out-tile = Os(32x128) @ Wd^T(128x128): A-frag rows=q, B-frag rows=out col
  f32x16 o2[4];
#pragma unroll
  for (int cc = 0; cc < 4; ++cc)
#pragma unroll
    for (int r = 0; r < 16; ++r) o2[cc][r] = 0.f;
  __builtin_amdgcn_s_setprio(1);
#pragma unroll
  for (int c = 0; c < 8; ++c) {
    bf16x8 af = *reinterpret_cast<const bf16x8*>(&Os[q][c * 16 + hi * 8]);
#pragma unroll
    for (int cc = 0; cc < 4; ++cc) {
      bf16x8 bfr = *reinterpret_cast<const bf16x8*>(&Wds[cc * 32 + q][c * 16 + hi * 8]);
      o2[cc] = MFMA32(af, bfr, o2[cc]);
    }
  }
  __builtin_amdgcn_s_setprio(0);

  float bdv[4];
#pragma unroll
  for (int cc = 0; cc < 4; ++cc) bdv[cc] = bd[cc * 32 + q];

#pragma unroll
  for (int r = 0; r < 16; ++r) {
    const int qr = (r & 3) + 8 * (r >> 2) + 4 * hi;
    long row = (long)b * 2048 + q0 + qr;
#pragma unroll
    for (int cc = 0; cc < 4; ++cc)
      Out[row * 128 + cc * 32 + q] = o2[cc][r] + bdv[cc];
  }
}

extern "C" void kernel_launch(void* const* d_in, const int* in_sizes, int n_in,
                              void* d_out, int out_size, void* d_ws, size_t ws_size,
                              hipStream_t stream)
{
  (void)in_sizes; (void)n_in; (void)out_size; (void)ws_size;
  const float* smiles = (const float*)d_in[0];
  const float* image  = (const float*)d_in[1];
  const float* Wv = (const float*)d_in[2]; const float* bv = (const float*)d_in[3];
  const float* Wk = (const float*)d_in[4]; const float* bk = (const float*)d_in[5];
  const float* Wq = (const float*)d_in[6]; const float* bq = (const float*)d_in[7];
  const float* Wd = (const float*)d_in[8]; const float* bd = (const float*)d_in[9];

  unsigned short* Qw = (unsigned short*)d_ws;          // [32][2048][128] bf16
  unsigned short* Kw = Qw + 8388608;                   // [32][2048][128] bf16
  unsigned short* Vw = Kw + 8388608;                   // [32][128][2048] bf16 (V^T)

  const float qscale = 1.4426950408889634f * 0.08838834764831845f;

  dim3 blk(256);
  proj_qkv_kernel<<<dim3(2048), blk, 0, stream>>>(image, Wq, bq, qscale,
                                                  smiles, Wk, bk, Wv, bv,
                                                  Qw, Kw, Vw);
  attn_kernel<<<dim3(512), blk, 0, stream>>>(Qw, Kw, Vw, Wd, bd, (float*)d_out);
}

// Round 20
// 114.348 us; speedup vs baseline: 2.4147x; 1.0372x over previous
//
#include <hip/hip_runtime.h>
#include <hip/hip_bf16.h>

typedef __attribute__((ext_vector_type(4))) float f32x4;
typedef __attribute__((ext_vector_type(16))) float f32x16;
typedef __attribute__((ext_vector_type(8))) short bf16x8;
typedef __attribute__((ext_vector_type(4))) unsigned int uint4v;
typedef __attribute__((ext_vector_type(2))) unsigned int uint2v;

#define MFMA16(a, b, c) __builtin_amdgcn_mfma_f32_16x16x32_bf16(a, b, c, 0, 0, 0)
#define MFMA32(a, b, c) __builtin_amdgcn_mfma_f32_32x32x16_bf16(a, b, c, 0, 0, 0)

__device__ __forceinline__ unsigned short f2bf(float f) {
  union { float f; unsigned u; } v; v.f = f;
  unsigned r = v.u + 0x7fffu + ((v.u >> 16) & 1u);
  return (unsigned short)(r >> 16);
}
__device__ __forceinline__ unsigned pack2(float a, float b) {
  union { __hip_bfloat162 h2; unsigned u; } cv;
  cv.h2 = __hip_bfloat162(__float2bfloat16(a), __float2bfloat16(b));
  return cv.u;
}

// cross-half exchange (validated R10-R19)
__device__ __forceinline__ void swap32(unsigned a, unsigned b, int hi,
                                       unsigned& ox, unsigned& oy) {
#if __has_builtin(__builtin_amdgcn_permlane32_swap)
  uint2v r = __builtin_amdgcn_permlane32_swap(a, b, false, false);
  ox = r[0]; oy = r[1];
#else
  unsigned sb = __shfl_xor(b, 32);
  unsigned sa = __shfl_xor(a, 32);
  ox = hi ? sb : a;
  oy = hi ? b : sa;
#endif
}

// Fused Q + K + V projections in ONE dispatch (2048 blocks) — R18-proven.
__global__ __launch_bounds__(256)
void proj_qkv_kernel(const float* __restrict__ image,
                     const float* __restrict__ Wq, const float* __restrict__ bq,
                     float qscale,
                     const float* __restrict__ smiles,
                     const float* __restrict__ Wk, const float* __restrict__ bk,
                     const float* __restrict__ Wv, const float* __restrict__ bv,
                     unsigned short* __restrict__ Qout,
                     unsigned short* __restrict__ Kout,
                     unsigned short* __restrict__ Vout)
{
  __shared__ __align__(16) unsigned short Ws[128][136];
  __shared__ __align__(16) unsigned short Xs[64][136];
  const int t = threadIdx.x;
  const int wid = t >> 6;
  const int lane = t & 63;
  const int ln = lane & 15, g = lane >> 4;
  const bool isQ = blockIdx.x < 1024;
  const long row0 = (long)(isQ ? blockIdx.x : blockIdx.x - 1024) * 64;
  const float* x = isQ ? image : smiles;

#pragma unroll
  for (int i = 0; i < 8; ++i) {
    int idx = (i * 256 + t) * 4;
    int r = idx >> 7, c = idx & 127;
    const float4 x4 = *reinterpret_cast<const float4*>(x + row0 * 128 + idx);
    ushort4 xb;
    xb.x = f2bf(x4.x); xb.y = f2bf(x4.y); xb.z = f2bf(x4.z); xb.w = f2bf(x4.w);
    *reinterpret_cast<ushort4*>(&Xs[r][c]) = xb;
  }

  const float* W1 = isQ ? Wq : Wk;
  const float* b1 = isQ ? bq : bk;
  float bz[8];
#pragma unroll
  for (int tt = 0; tt < 8; ++tt) bz[tt] = b1[tt * 16 + ln];

#pragma unroll
  for (int i = 0; i < 16; ++i) {
    int idx = (i * 256 + t) * 4;
    int r = idx >> 7, c = idx & 127;
    const float4 w4 = *reinterpret_cast<const float4*>(W1 + idx);
    ushort4 wb;
    wb.x = f2bf(w4.x); wb.y = f2bf(w4.y); wb.z = f2bf(w4.z); wb.w = f2bf(w4.w);
    *reinterpret_cast<ushort4*>(&Ws[r][c]) = wb;
  }
  __syncthreads();

  f32x4 acc[8];
#pragma unroll
  for (int tt = 0; tt < 8; ++tt) acc[tt] = (f32x4){0.f, 0.f, 0.f, 0.f};
#pragma unroll
  for (int c = 0; c < 4; ++c) {
    bf16x8 af = *reinterpret_cast<const bf16x8*>(&Xs[wid * 16 + ln][c * 32 + g * 8]);
#pragma unroll
    for (int tt = 0; tt < 8; ++tt) {
      bf16x8 bfr = *reinterpret_cast<const bf16x8*>(&Ws[tt * 16 + ln][c * 32 + g * 8]);
      acc[tt] = MFMA16(af, bfr, acc[tt]);
    }
  }

  if (isQ) {
#pragma unroll
    for (int tt = 0; tt < 8; ++tt)
#pragma unroll
      for (int r = 0; r < 4; ++r) {
        long row = row0 + wid * 16 + g * 4 + r;
        Qout[row * 128 + tt * 16 + ln] = f2bf((acc[tt][r] + bz[tt]) * qscale);
      }
    return;
  }

#pragma unroll
  for (int tt = 0; tt < 8; ++tt)
#pragma unroll
    for (int r = 0; r < 4; ++r) {
      long row = row0 + wid * 16 + g * 4 + r;
      Kout[row * 128 + tt * 16 + ln] = f2bf(acc[tt][r] + bz[tt]);
    }

  __syncthreads();
#pragma unroll
  for (int i = 0; i < 16; ++i) {
    int idx = (i * 256 + t) * 4;
    int r = idx >> 7, c = idx & 127;
    const float4 w4 = *reinterpret_cast<const float4*>(Wv + idx);
    ushort4 wb;
    wb.x = f2bf(w4.x); wb.y = f2bf(w4.y); wb.z = f2bf(w4.z); wb.w = f2bf(w4.w);
    *reinterpret_cast<ushort4*>(&Ws[r][c]) = wb;
  }
  __syncthreads();

  float bzv[8];
#pragma unroll
  for (int tt = 0; tt < 8; ++tt) bzv[tt] = bv[tt * 16 + ln];
#pragma unroll
  for (int tt = 0; tt < 8; ++tt) acc[tt] = (f32x4){0.f, 0.f, 0.f, 0.f};
#pragma unroll
  for (int c = 0; c < 4; ++c) {
    bf16x8 af = *reinterpret_cast<const bf16x8*>(&Xs[wid * 16 + ln][c * 32 + g * 8]);
#pragma unroll
    for (int tt = 0; tt < 8; ++tt) {
      bf16x8 bfr = *reinterpret_cast<const bf16x8*>(&Ws[tt * 16 + ln][c * 32 + g * 8]);
      acc[tt] = MFMA16(af, bfr, acc[tt]);
    }
  }
#pragma unroll
  for (int tt = 0; tt < 8; ++tt)
#pragma unroll
    for (int r = 0; r < 4; ++r) {
      long row = row0 + wid * 16 + g * 4 + r;
      long bb = row >> 11, rr = row & 2047;
      Vout[(bb * 128 + tt * 16 + ln) * 2048 + rr] = f2bf(acc[tt][r] + bzv[tt]);
    }
}

// Flash attention, 8 waves x 32 q (512 threads, 256 q-rows/block, grid 256):
// per-CU-iter LDS ops drop 160 -> 144 (K/V tile written ONCE per CU instead of
// twice — writes amortize over 8 waves). Same R18 single-barrier dbuf loop,
// same per-wave body, same fused Wd epilogue. 1 block/CU x 8 waves = 2/SIMD.
__global__ __launch_bounds__(512)
void attn_kernel(const unsigned short* __restrict__ Qg,
                 const unsigned short* __restrict__ Kg,
                 const unsigned short* __restrict__ Vtg,
                 const float* __restrict__ Wd,
                 const float* __restrict__ bd,
                 float* __restrict__ Out)
{
  // main loop: Ks[2][32][136] (17408 B) + Vs[2][128][40] (20480 B) = 37888
  // epilogue : Wds[128][136] (34816 B) + 8 x Os[32][136] (8704 B) = 104448
  __shared__ __align__(16) unsigned char smem[104448];
  auto Ks = reinterpret_cast<unsigned short (*)[32][136]>(smem);
  auto Vs = reinterpret_cast<unsigned short (*)[128][40]>(smem + 17408);

  const int t = threadIdx.x;          // 0..511
  const int lane = t & 63;
  const int q = lane & 31;
  const int hi = lane >> 5;
  const int wid = t >> 6;             // 0..7

  // XCD swizzle over 256 blocks: all 8 q-blocks (256 rows each) of a batch on
  // one XCD. gbid -> xcd r_=gbid&7; k_=gbid>>3: b = r_+8*(k_>>3), j = k_&7.
  const int gbid = blockIdx.x;
  const int k_ = gbid >> 3, r_ = gbid & 7;
  const int b = r_ + 8 * (k_ >> 3);
  const int j = k_ & 7;
  const int q0 = j * 256 + wid * 32;

  const unsigned short* Qb = Qg + (long)b * 2048 * 128;
  const unsigned short* Kb = Kg + (long)b * 2048 * 128;
  const unsigned short* Vb = Vtg + (long)b * 128 * 2048;

  // staging: exactly 1 b128 per thread for each of K and V (512 threads)
  const int kr = t >> 4, kc = (t & 15) * 8;   // K tile [32][128]
  const int vc = t >> 2, ko = (t & 3) * 8;    // V^T tile [128][32]

  bf16x8 qf[8];
#pragma unroll
  for (int c = 0; c < 8; ++c)
    qf[c] = *reinterpret_cast<const bf16x8*>(
        Qb + (long)(q0 + q) * 128 + c * 16 + hi * 8);

  f32x16 o[4];
#pragma unroll
  for (int dc = 0; dc < 4; ++dc)
#pragma unroll
    for (int r = 0; r < 16; ++r) o[dc][r] = 0.f;
  float mrun = -1e30f;
  float lrun = 0.f;

  // prologue: tile 0 -> buf0; then issue tile 1's loads (T14)
  uint4v kreg = *reinterpret_cast<const uint4v*>(Kb + (long)kr * 128 + kc);
  uint4v vreg = *reinterpret_cast<const uint4v*>(Vb + (long)vc * 2048 + ko);
  *reinterpret_cast<uint4v*>(&Ks[0][kr][kc]) = kreg;
  *reinterpret_cast<uint4v*>(&Vs[0][vc][ko]) = vreg;
  kreg = *reinterpret_cast<const uint4v*>(Kb + (long)(32 + kr) * 128 + kc);
  vreg = *reinterpret_cast<const uint4v*>(Vb + (long)vc * 2048 + 32 + ko);
  __syncthreads();

  for (int kt = 0; kt < 64; ++kt) {
    const int cur = kt & 1;

    // publish tile kt+1 into the other buffer (disjoint from this iter's reads)
    if (kt < 63) {
      const int nb = cur ^ 1;
      *reinterpret_cast<uint4v*>(&Ks[nb][kr][kc]) = kreg;
      *reinterpret_cast<uint4v*>(&Vs[nb][vc][ko]) = vreg;
      if (kt < 62) {   // issue tile kt+2's loads — a full iteration of slack
        const int nv0 = (kt + 2) * 32;
        kreg = *reinterpret_cast<const uint4v*>(Kb + (long)(nv0 + kr) * 128 + kc);
        vreg = *reinterpret_cast<const uint4v*>(Vb + (long)vc * 2048 + nv0 + ko);
      }
    }

    // QK^T from buf[cur]
    f32x16 st;
#pragma unroll
    for (int r = 0; r < 16; ++r) st[r] = 0.f;
    __builtin_amdgcn_s_setprio(1);
#pragma unroll
    for (int c = 0; c < 8; ++c) {
      bf16x8 kf = *reinterpret_cast<const bf16x8*>(&Ks[cur][q][c * 16 + hi * 8]);
      st = MFMA32(kf, qf[c], st);
    }
    __builtin_amdgcn_s_setprio(0);

    float tm = st[0];
#pragma unroll
    for (int r = 1; r < 16; ++r) tm = fmaxf(tm, st[r]);
    tm = fmaxf(tm, __shfl_xor(tm, 32));

    float mcur = mrun;
    if (!__all(tm <= mcur + 8.0f)) {
      float mnew = fmaxf(mcur, tm);
      float al = __builtin_amdgcn_exp2f(mcur - mnew);
      mrun = mnew;
      mcur = mnew;
      lrun *= al;
#pragma unroll
      for (int r = 0; r < 16; ++r) {
        float ar = __shfl(al, (r & 3) + 8 * (r >> 2) + 4 * hi);
#pragma unroll
        for (int dc = 0; dc < 4; ++dc) o[dc][r] *= ar;
      }
    }

    unsigned pk[8];
    float s[8];
#pragma unroll
    for (int j2 = 0; j2 < 8; ++j2) {
      float pa_ = __builtin_amdgcn_exp2f(st[2 * j2] - mcur);
      float pb_ = __builtin_amdgcn_exp2f(st[2 * j2 + 1] - mcur);
      s[j2] = pa_ + pb_;
      pk[j2] = pack2(pa_, pb_);
    }
#pragma unroll
    for (int j2 = 0; j2 < 4; ++j2) s[j2] += s[j2 + 4];
    lrun += (s[0] + s[1]) + (s[2] + s[3]);

    union { unsigned u[4]; bf16x8 v; } pa0, pa1;
    swap32(pk[0], pk[2], hi, pa0.u[0], pa0.u[2]);
    swap32(pk[1], pk[3], hi, pa0.u[1], pa0.u[3]);
    swap32(pk[4], pk[6], hi, pa1.u[0], pa1.u[2]);
    swap32(pk[5], pk[7], hi, pa1.u[1], pa1.u[3]);

    // PV from buf[cur]
    __builtin_amdgcn_s_setprio(1);
#pragma unroll
    for (int dc = 0; dc < 4; ++dc) {
      bf16x8 vf0 = *reinterpret_cast<const bf16x8*>(&Vs[cur][dc * 32 + q][hi * 8]);
      bf16x8 vf1 = *reinterpret_cast<const bf16x8*>(&Vs[cur][dc * 32 + q][16 + hi * 8]);
      o[dc] = MFMA32(pa0.v, vf0, o[dc]);
      o[dc] = MFMA32(pa1.v, vf1, o[dc]);
    }
    __builtin_amdgcn_s_setprio(0);

    __syncthreads();   // single barrier per iteration
  }

  // ---------- fused output projection: out = O @ Wd^T + bd ----------
  auto Wds = reinterpret_cast<unsigned short (*)[136]>(smem);
  auto Os  = reinterpret_cast<unsigned short (*)[136]>(smem + 34816 + wid * 8704);

  // stage Wd -> bf16 LDS [128][136] (512 threads cooperatively)
#pragma unroll
  for (int i = 0; i < 8; ++i) {
    int idx = (i * 512 + t) * 4;
    int r = idx >> 7, c = idx & 127;
    const float4 w4 = *reinterpret_cast<const float4*>(Wd + idx);
    ushort4 wb;
    wb.x = f2bf(w4.x); wb.y = f2bf(w4.y); wb.z = f2bf(w4.z); wb.w = f2bf(w4.w);
    *reinterpret_cast<ushort4*>(&Wds[r][c]) = wb;
  }

  // write normalized O (bf16) into per-wave Os[32 q][128 d]
  float ltot = lrun + __shfl_xor(lrun, 32);
  float inv = 1.f / ltot;     // valid for row q = lane&31
#pragma unroll
  for (int r = 0; r < 16; ++r) {
    const int qr = (r & 3) + 8 * (r >> 2) + 4 * hi;
    float invr = __shfl(inv, qr);
#pragma unroll
    for (int dc = 0; dc < 4; ++dc)
      Os[qr][dc * 32 + q] = f2bf(o[dc][r] * invr);
  }
  __syncthreads();

  // out-tile = Os(32x128) @ Wd^T(128x128)
  f32x16 o2[4];
#pragma unroll
  for (int cc = 0; cc < 4; ++cc)
#pragma unroll
    for (int r = 0; r < 16; ++r) o2[cc][r] = 0.f;
  __builtin_amdgcn_s_setprio(1);
#pragma unroll
  for (int c = 0; c < 8; ++c) {
    bf16x8 af = *reinterpret_cast<const bf16x8*>(&Os[q][c * 16 + hi * 8]);
#pragma unroll
    for (int cc = 0; cc < 4; ++cc) {
      bf16x8 bfr = *reinterpret_cast<const bf16x8*>(&Wds[cc * 32 + q][c * 16 + hi * 8]);
      o2[cc] = MFMA32(af, bfr, o2[cc]);
    }
  }
  __builtin_amdgcn_s_setprio(0);

  float bdv[4];
#pragma unroll
  for (int cc = 0; cc < 4; ++cc) bdv[cc] = bd[cc * 32 + q];

#pragma unroll
  for (int r = 0; r < 16; ++r) {
    const int qr = (r & 3) + 8 * (r >> 2) + 4 * hi;
    long row = (long)b * 2048 + q0 + qr;
#pragma unroll
    for (int cc = 0; cc < 4; ++cc)
      Out[row * 128 + cc * 32 + q] = o2[cc][r] + bdv[cc];
  }
}

extern "C" void kernel_launch(void* const* d_in, const int* in_sizes, int n_in,
                              void* d_out, int out_size, void* d_ws, size_t ws_size,
                              hipStream_t stream)
{
  (void)in_sizes; (void)n_in; (void)out_size; (void)ws_size;
  const float* smiles = (const float*)d_in[0];
  const float* image  = (const float*)d_in[1];
  const float* Wv = (const float*)d_in[2]; const float* bv = (const float*)d_in[3];
  const float* Wk = (const float*)d_in[4]; const float* bk = (const float*)d_in[5];
  const float* Wq = (const float*)d_in[6]; const float* bq = (const float*)d_in[7];
  const float* Wd = (const float*)d_in[8]; const float* bd = (const float*)d_in[9];

  unsigned short* Qw = (unsigned short*)d_ws;          // [32][2048][128] bf16
  unsigned short* Kw = Qw + 8388608;                   // [32][2048][128] bf16
  unsigned short* Vw = Kw + 8388608;                   // [32][128][2048] bf16 (V^T)

  const float qscale = 1.4426950408889634f * 0.08838834764831845f;

  proj_qkv_kernel<<<dim3(2048), dim3(256), 0, stream>>>(image, Wq, bq, qscale,
                                                        smiles, Wk, bk, Wv, bv,
                                                        Qw, Kw, Vw);
  attn_kernel<<<dim3(256), dim3(512), 0, stream>>>(Qw, Kw, Vw, Wd, bd, (float*)d_out);
}

// Round 23
// 114.139 us; speedup vs baseline: 2.4191x; 1.0018x over previous
//
#include <hip/hip_runtime.h>
#include <hip/hip_bf16.h>

typedef __attribute__((ext_vector_type(4))) float f32x4;
typedef __attribute__((ext_vector_type(16))) float f32x16;
typedef __attribute__((ext_vector_type(8))) short bf16x8;
typedef __attribute__((ext_vector_type(4))) unsigned int uint4v;
typedef __attribute__((ext_vector_type(2))) unsigned int uint2v;

#define MFMA16(a, b, c) __builtin_amdgcn_mfma_f32_16x16x32_bf16(a, b, c, 0, 0, 0)
#define MFMA32(a, b, c) __builtin_amdgcn_mfma_f32_32x32x16_bf16(a, b, c, 0, 0, 0)

__device__ __forceinline__ unsigned short f2bf(float f) {
  union { float f; unsigned u; } v; v.f = f;
  unsigned r = v.u + 0x7fffu + ((v.u >> 16) & 1u);
  return (unsigned short)(r >> 16);
}
__device__ __forceinline__ unsigned pack2(float a, float b) {
  union { __hip_bfloat162 h2; unsigned u; } cv;
  cv.h2 = __hip_bfloat162(__float2bfloat16(a), __float2bfloat16(b));
  return cv.u;
}

// cross-half exchange (validated R10-R20)
__device__ __forceinline__ void swap32(unsigned a, unsigned b, int hi,
                                       unsigned& ox, unsigned& oy) {
#if __has_builtin(__builtin_amdgcn_permlane32_swap)
  uint2v r = __builtin_amdgcn_permlane32_swap(a, b, false, false);
  ox = r[0]; oy = r[1];
#else
  unsigned sb = __shfl_xor(b, 32);
  unsigned sa = __shfl_xor(a, 32);
  ox = hi ? sb : a;
  oy = hi ? b : sa;
#endif
}

// Fused Q + K + V projections in ONE dispatch (2048 blocks) — R18-proven.
__global__ __launch_bounds__(256)
void proj_qkv_kernel(const float* __restrict__ image,
                     const float* __restrict__ Wq, const float* __restrict__ bq,
                     float qscale,
                     const float* __restrict__ smiles,
                     const float* __restrict__ Wk, const float* __restrict__ bk,
                     const float* __restrict__ Wv, const float* __restrict__ bv,
                     unsigned short* __restrict__ Qout,
                     unsigned short* __restrict__ Kout,
                     unsigned short* __restrict__ Vout)
{
  __shared__ __align__(16) unsigned short Ws[128][136];
  __shared__ __align__(16) unsigned short Xs[64][136];
  const int t = threadIdx.x;
  const int wid = t >> 6;
  const int lane = t & 63;
  const int ln = lane & 15, g = lane >> 4;
  const bool isQ = blockIdx.x < 1024;
  const long row0 = (long)(isQ ? blockIdx.x : blockIdx.x - 1024) * 64;
  const float* x = isQ ? image : smiles;

#pragma unroll
  for (int i = 0; i < 8; ++i) {
    int idx = (i * 256 + t) * 4;
    int r = idx >> 7, c = idx & 127;
    const float4 x4 = *reinterpret_cast<const float4*>(x + row0 * 128 + idx);
    ushort4 xb;
    xb.x = f2bf(x4.x); xb.y = f2bf(x4.y); xb.z = f2bf(x4.z); xb.w = f2bf(x4.w);
    *reinterpret_cast<ushort4*>(&Xs[r][c]) = xb;
  }

  const float* W1 = isQ ? Wq : Wk;
  const float* b1 = isQ ? bq : bk;
  float bz[8];
#pragma unroll
  for (int tt = 0; tt < 8; ++tt) bz[tt] = b1[tt * 16 + ln];

#pragma unroll
  for (int i = 0; i < 16; ++i) {
    int idx = (i * 256 + t) * 4;
    int r = idx >> 7, c = idx & 127;
    const float4 w4 = *reinterpret_cast<const float4*>(W1 + idx);
    ushort4 wb;
    wb.x = f2bf(w4.x); wb.y = f2bf(w4.y); wb.z = f2bf(w4.z); wb.w = f2bf(w4.w);
    *reinterpret_cast<ushort4*>(&Ws[r][c]) = wb;
  }
  __syncthreads();

  f32x4 acc[8];
#pragma unroll
  for (int tt = 0; tt < 8; ++tt) acc[tt] = (f32x4){0.f, 0.f, 0.f, 0.f};
#pragma unroll
  for (int c = 0; c < 4; ++c) {
    bf16x8 af = *reinterpret_cast<const bf16x8*>(&Xs[wid * 16 + ln][c * 32 + g * 8]);
#pragma unroll
    for (int tt = 0; tt < 8; ++tt) {
      bf16x8 bfr = *reinterpret_cast<const bf16x8*>(&Ws[tt * 16 + ln][c * 32 + g * 8]);
      acc[tt] = MFMA16(af, bfr, acc[tt]);
    }
  }

  if (isQ) {
#pragma unroll
    for (int tt = 0; tt < 8; ++tt)
#pragma unroll
      for (int r = 0; r < 4; ++r) {
        long row = row0 + wid * 16 + g * 4 + r;
        Qout[row * 128 + tt * 16 + ln] = f2bf((acc[tt][r] + bz[tt]) * qscale);
      }
    return;
  }

#pragma unroll
  for (int tt = 0; tt < 8; ++tt)
#pragma unroll
    for (int r = 0; r < 4; ++r) {
      long row = row0 + wid * 16 + g * 4 + r;
      Kout[row * 128 + tt * 16 + ln] = f2bf(acc[tt][r] + bz[tt]);
    }

  __syncthreads();
#pragma unroll
  for (int i = 0; i < 16; ++i) {
    int idx = (i * 256 + t) * 4;
    int r = idx >> 7, c = idx & 127;
    const float4 w4 = *reinterpret_cast<const float4*>(Wv + idx);
    ushort4 wb;
    wb.x = f2bf(w4.x); wb.y = f2bf(w4.y); wb.z = f2bf(w4.z); wb.w = f2bf(w4.w);
    *reinterpret_cast<ushort4*>(&Ws[r][c]) = wb;
  }
  __syncthreads();

  float bzv[8];
#pragma unroll
  for (int tt = 0; tt < 8; ++tt) bzv[tt] = bv[tt * 16 + ln];
#pragma unroll
  for (int tt = 0; tt < 8; ++tt) acc[tt] = (f32x4){0.f, 0.f, 0.f, 0.f};
#pragma unroll
  for (int c = 0; c < 4; ++c) {
    bf16x8 af = *reinterpret_cast<const bf16x8*>(&Xs[wid * 16 + ln][c * 32 + g * 8]);
#pragma unroll
    for (int tt = 0; tt < 8; ++tt) {
      bf16x8 bfr = *reinterpret_cast<const bf16x8*>(&Ws[tt * 16 + ln][c * 32 + g * 8]);
      acc[tt] = MFMA16(af, bfr, acc[tt]);
    }
  }
#pragma unroll
  for (int tt = 0; tt < 8; ++tt)
#pragma unroll
    for (int r = 0; r < 4; ++r) {
      long row = row0 + wid * 16 + g * 4 + r;
      long bb = row >> 11, rr = row & 2047;
      Vout[(bb * 128 + tt * 16 + ln) * 2048 + rr] = f2bf(acc[tt][r] + bzv[tt]);
    }
}

// Flash attention, 8 waves x 32 q, KVBLK=64 (32 iterations): halves barrier
// count and softmax-pass count per kv; QK^T is two independent 8-MFMA chains.
// Single-barrier dbuf (R18-proven skeleton), T14 prefetch, defer-max,
// permlane P-exchange (R11-validated 64-kv softmax body), fused Wd epilogue.
__global__ __launch_bounds__(512)
void attn_kernel(const unsigned short* __restrict__ Qg,
                 const unsigned short* __restrict__ Kg,
                 const unsigned short* __restrict__ Vtg,
                 const float* __restrict__ Wd,
                 const float* __restrict__ bd,
                 float* __restrict__ Out)
{
  // main loop: Ks[2][64][136] (34816 B) + Vs[2][128][72] (36864 B) = 71680
  // epilogue : Wds[128][136] (34816 B) + 8 x Os[32][136] (8704 B) = 104448
  __shared__ __align__(16) unsigned char smem[104448];
  auto Ks = reinterpret_cast<unsigned short (*)[64][136]>(smem);
  auto Vs = reinterpret_cast<unsigned short (*)[128][72]>(smem + 34816);

  const int t = threadIdx.x;          // 0..511
  const int lane = t & 63;
  const int q = lane & 31;
  const int hi = lane >> 5;
  const int wid = t >> 6;             // 0..7

  // XCD swizzle over 256 blocks (R20): all 8 q-blocks of a batch on one XCD
  const int gbid = blockIdx.x;
  const int k_ = gbid >> 3, r_ = gbid & 7;
  const int b = r_ + 8 * (k_ >> 3);
  const int j = k_ & 7;
  const int q0 = j * 256 + wid * 32;

  const unsigned short* Qb = Qg + (long)b * 2048 * 128;
  const unsigned short* Kb = Kg + (long)b * 2048 * 128;
  const unsigned short* Vb = Vtg + (long)b * 128 * 2048;

  // staging: 2 b128 per thread for each of K and V (512 threads)
  const int kr = t >> 3, kc = (t & 7) * 16;   // K tile [64][128]
  const int vc = t >> 2, vo = (t & 3) * 16;   // V^T tile [128][64]

  bf16x8 qf[8];
#pragma unroll
  for (int c = 0; c < 8; ++c)
    qf[c] = *reinterpret_cast<const bf16x8*>(
        Qb + (long)(q0 + q) * 128 + c * 16 + hi * 8);

  f32x16 o[4];
#pragma unroll
  for (int dc = 0; dc < 4; ++dc)
#pragma unroll
    for (int r = 0; r < 16; ++r) o[dc][r] = 0.f;
  float mrun = -1e30f;
  float lrun = 0.f;

  // prologue: tile 0 -> buf0; then issue tile 1's loads (T14)
  uint4v kregA = *reinterpret_cast<const uint4v*>(Kb + (long)kr * 128 + kc);
  uint4v kregB = *reinterpret_cast<const uint4v*>(Kb + (long)kr * 128 + kc + 8);
  uint4v vregA = *reinterpret_cast<const uint4v*>(Vb + (long)vc * 2048 + vo);
  uint4v vregB = *reinterpret_cast<const uint4v*>(Vb + (long)vc * 2048 + vo + 8);
  *reinterpret_cast<uint4v*>(&Ks[0][kr][kc]) = kregA;
  *reinterpret_cast<uint4v*>(&Ks[0][kr][kc + 8]) = kregB;
  *reinterpret_cast<uint4v*>(&Vs[0][vc][vo]) = vregA;
  *reinterpret_cast<uint4v*>(&Vs[0][vc][vo + 8]) = vregB;
  kregA = *reinterpret_cast<const uint4v*>(Kb + (long)(64 + kr) * 128 + kc);
  kregB = *reinterpret_cast<const uint4v*>(Kb + (long)(64 + kr) * 128 + kc + 8);
  vregA = *reinterpret_cast<const uint4v*>(Vb + (long)vc * 2048 + 64 + vo);
  vregB = *reinterpret_cast<const uint4v*>(Vb + (long)vc * 2048 + 64 + vo + 8);
  __syncthreads();

  for (int kt = 0; kt < 32; ++kt) {
    const int cur = kt & 1;

    // publish tile kt+1 into the other buffer (disjoint from this iter's reads)
    if (kt < 31) {
      const int nb = cur ^ 1;
      *reinterpret_cast<uint4v*>(&Ks[nb][kr][kc]) = kregA;
      *reinterpret_cast<uint4v*>(&Ks[nb][kr][kc + 8]) = kregB;
      *reinterpret_cast<uint4v*>(&Vs[nb][vc][vo]) = vregA;
      *reinterpret_cast<uint4v*>(&Vs[nb][vc][vo + 8]) = vregB;
      if (kt < 30) {   // issue tile kt+2's loads — a full iteration of slack
        const int nv0 = (kt + 2) * 64;
        kregA = *reinterpret_cast<const uint4v*>(Kb + (long)(nv0 + kr) * 128 + kc);
        kregB = *reinterpret_cast<const uint4v*>(Kb + (long)(nv0 + kr) * 128 + kc + 8);
        vregA = *reinterpret_cast<const uint4v*>(Vb + (long)vc * 2048 + nv0 + vo);
        vregB = *reinterpret_cast<const uint4v*>(Vb + (long)vc * 2048 + nv0 + vo + 8);
      }
    }

    // QK^T: two independent accumulator chains (kv 0..31 and 32..63)
    f32x16 st0, st1;
#pragma unroll
    for (int r = 0; r < 16; ++r) { st0[r] = 0.f; st1[r] = 0.f; }
    __builtin_amdgcn_s_setprio(1);
#pragma unroll
    for (int c = 0; c < 8; ++c) {
      bf16x8 kf0 = *reinterpret_cast<const bf16x8*>(&Ks[cur][q][c * 16 + hi * 8]);
      bf16x8 kf1 = *reinterpret_cast<const bf16x8*>(&Ks[cur][32 + q][c * 16 + hi * 8]);
      st0 = MFMA32(kf0, qf[c], st0);
      st1 = MFMA32(kf1, qf[c], st1);
    }
    __builtin_amdgcn_s_setprio(0);

    // tile max (tree over 32 values) + cross-hi
    float mx[16];
#pragma unroll
    for (int r = 0; r < 16; ++r) mx[r] = fmaxf(st0[r], st1[r]);
#pragma unroll
    for (int r = 0; r < 8; ++r) mx[r] = fmaxf(mx[r], mx[r + 8]);
#pragma unroll
    for (int r = 0; r < 4; ++r) mx[r] = fmaxf(mx[r], mx[r + 4]);
    float tm = fmaxf(fmaxf(mx[0], mx[1]), fmaxf(mx[2], mx[3]));
    tm = fmaxf(tm, __shfl_xor(tm, 32));

    // defer-max rescale (once per 64 kv)
    float mcur = mrun;
    if (!__all(tm <= mcur + 8.0f)) {
      float mnew = fmaxf(mcur, tm);
      float al = __builtin_amdgcn_exp2f(mcur - mnew);
      mrun = mnew;
      mcur = mnew;
      lrun *= al;
#pragma unroll
      for (int r = 0; r < 16; ++r) {
        float ar = __shfl(al, (r & 3) + 8 * (r >> 2) + 4 * hi);
#pragma unroll
        for (int dc = 0; dc < 4; ++dc) o[dc][r] *= ar;
      }
    }

    // exp2 + pack pairs + partial sums (R11-validated)
    unsigned pk[16];
    float s[16];
#pragma unroll
    for (int j2 = 0; j2 < 8; ++j2) {
      float pa_ = __builtin_amdgcn_exp2f(st0[2 * j2] - mcur);
      float pb_ = __builtin_amdgcn_exp2f(st0[2 * j2 + 1] - mcur);
      s[j2] = pa_ + pb_;
      pk[j2] = pack2(pa_, pb_);
    }
#pragma unroll
    for (int j2 = 0; j2 < 8; ++j2) {
      float pa_ = __builtin_amdgcn_exp2f(st1[2 * j2] - mcur);
      float pb_ = __builtin_amdgcn_exp2f(st1[2 * j2 + 1] - mcur);
      s[8 + j2] = pa_ + pb_;
      pk[8 + j2] = pack2(pa_, pb_);
    }
#pragma unroll
    for (int j2 = 0; j2 < 8; ++j2) s[j2] += s[j2 + 8];
#pragma unroll
    for (int j2 = 0; j2 < 4; ++j2) s[j2] += s[j2 + 4];
    lrun += (s[0] + s[1]) + (s[2] + s[3]);

    // assemble PV A-fragments via cross-half swaps
    union { unsigned u[4]; bf16x8 v; } pa0, pa1, pa2, pa3;
    swap32(pk[0],  pk[2],  hi, pa0.u[0], pa0.u[2]);
    swap32(pk[1],  pk[3],  hi, pa0.u[1], pa0.u[3]);
    swap32(pk[4],  pk[6],  hi, pa1.u[0], pa1.u[2]);
    swap32(pk[5],  pk[7],  hi, pa1.u[1], pa1.u[3]);
    swap32(pk[8],  pk[10], hi, pa2.u[0], pa2.u[2]);
    swap32(pk[9],  pk[11], hi, pa2.u[1], pa2.u[3]);
    swap32(pk[12], pk[14], hi, pa3.u[0], pa3.u[2]);
    swap32(pk[13], pk[15], hi, pa3.u[1], pa3.u[3]);

    // PV: O[q][d] += P[q][kv] V[kv][d], 4 kv-subtiles x 4 d-chunks
    __builtin_amdgcn_s_setprio(1);
#pragma unroll
    for (int dc = 0; dc < 4; ++dc) {
      bf16x8 vf0 = *reinterpret_cast<const bf16x8*>(&Vs[cur][dc * 32 + q][hi * 8]);
      bf16x8 vf1 = *reinterpret_cast<const bf16x8*>(&Vs[cur][dc * 32 + q][16 + hi * 8]);
      bf16x8 vf2 = *reinterpret_cast<const bf16x8*>(&Vs[cur][dc * 32 + q][32 + hi * 8]);
      bf16x8 vf3 = *reinterpret_cast<const bf16x8*>(&Vs[cur][dc * 32 + q][48 + hi * 8]);
      o[dc] = MFMA32(pa0.v, vf0, o[dc]);
      o[dc] = MFMA32(pa1.v, vf1, o[dc]);
      o[dc] = MFMA32(pa2.v, vf2, o[dc]);
      o[dc] = MFMA32(pa3.v, vf3, o[dc]);
    }
    __builtin_amdgcn_s_setprio(0);

    __syncthreads();   // single barrier per iteration
  }

  // ---------- fused output projection: out = O @ Wd^T + bd ----------
  auto Wds = reinterpret_cast<unsigned short (*)[136]>(smem);
  auto Os  = reinterpret_cast<unsigned short (*)[136]>(smem + 34816 + wid * 8704);

  // stage Wd -> bf16 LDS [128][136] (512 threads cooperatively)
#pragma unroll
  for (int i = 0; i < 8; ++i) {
    int idx = (i * 512 + t) * 4;
    int r = idx >> 7, c = idx & 127;
    const float4 w4 = *reinterpret_cast<const float4*>(Wd + idx);
    ushort4 wb;
    wb.x = f2bf(w4.x); wb.y = f2bf(w4.y); wb.z = f2bf(w4.z); wb.w = f2bf(w4.w);
    *reinterpret_cast<ushort4*>(&Wds[r][c]) = wb;
  }

  // write normalized O (bf16) into per-wave Os[32 q][128 d]
  float ltot = lrun + __shfl_xor(lrun, 32);
  float inv = 1.f / ltot;     // valid for row q = lane&31
#pragma unroll
  for (int r = 0; r < 16; ++r) {
    const int qr = (r & 3) + 8 * (r >> 2) + 4 * hi;
    float invr = __shfl(inv, qr);
#pragma unroll
    for (int dc = 0; dc < 4; ++dc)
      Os[qr][dc * 32 + q] = f2bf(o[dc][r] * invr);
  }
  __syncthreads();

  // out-tile = Os(32x128) @ Wd^T(128x128)
  f32x16 o2[4];
#pragma unroll
  for (int cc = 0; cc < 4; ++cc)
#pragma unroll
    for (int r = 0; r < 16; ++r) o2[cc][r] = 0.f;
  __builtin_amdgcn_s_setprio(1);
#pragma unroll
  for (int c = 0; c < 8; ++c) {
    bf16x8 af = *reinterpret_cast<const bf16x8*>(&Os[q][c * 16 + hi * 8]);
#pragma unroll
    for (int cc = 0; cc < 4; ++cc) {
      bf16x8 bfr = *reinterpret_cast<const bf16x8*>(&Wds[cc * 32 + q][c * 16 + hi * 8]);
      o2[cc] = MFMA32(af, bfr, o2[cc]);
    }
  }
  __builtin_amdgcn_s_setprio(0);

  float bdv[4];
#pragma unroll
  for (int cc = 0; cc < 4; ++cc) bdv[cc] = bd[cc * 32 + q];

#pragma unroll
  for (int r = 0; r < 16; ++r) {
    const int qr = (r & 3) + 8 * (r >> 2) + 4 * hi;
    long row = (long)b * 2048 + q0 + qr;
#pragma unroll
    for (int cc = 0; cc < 4; ++cc)
      Out[row * 128 + cc * 32 + q] = o2[cc][r] + bdv[cc];
  }
}

extern "C" void kernel_launch(void* const* d_in, const int* in_sizes, int n_in,
                              void* d_out, int out_size, void* d_ws, size_t ws_size,
                              hipStream_t stream)
{
  (void)in_sizes; (void)n_in; (void)out_size; (void)ws_size;
  const float* smiles = (const float*)d_in[0];
  const float* image  = (const float*)d_in[1];
  const float* Wv = (const float*)d_in[2]; const float* bv = (const float*)d_in[3];
  const float* Wk = (const float*)d_in[4]; const float* bk = (const float*)d_in[5];
  const float* Wq = (const float*)d_in[6]; const float* bq = (const float*)d_in[7];
  const float* Wd = (const float*)d_in[8]; const float* bd = (const float*)d_in[9];

  unsigned short* Qw = (unsigned short*)d_ws;          // [32][2048][128] bf16
  unsigned short* Kw = Qw + 8388608;                   // [32][2048][128] bf16
  unsigned short* Vw = Kw + 8388608;                   // [32][128][2048] bf16 (V^T)

  const float qscale = 1.4426950408889634f * 0.08838834764831845f;

  proj_qkv_kernel<<<dim3(2048), dim3(256), 0, stream>>>(image, Wq, bq, qscale,
                                                        smiles, Wk, bk, Wv, bv,
                                                        Qw, Kw, Vw);
  attn_kernel<<<dim3(256), dim3(512), 0, stream>>>(Qw, Kw, Vw, Wd, bd, (float*)d_out);
}